// Round 1
// baseline (238.705 us; speedup 1.0000x reference)
//
#include <hip/hip_runtime.h>
#include <hip/hip_bf16.h>

#define B_ 8192
#define F_ 1024
#define P_ 160
#define C_ 10

typedef __attribute__((ext_vector_type(8))) short short8;
typedef __attribute__((ext_vector_type(4))) float f32x4;

// ---- helpers -------------------------------------------------------------

// pack two f32 -> two bf16 (RNE) in one u32 (low = a, high = b)
__device__ inline unsigned pk2(float a, float b) {
    __hip_bfloat162 h = __float22bfloat162_rn(make_float2(a, b));
    return *reinterpret_cast<unsigned*>(&h);
}
__device__ inline float lo_f(unsigned u) { return __uint_as_float(u << 16); }
__device__ inline float hi_f(unsigned u) { return __uint_as_float(u & 0xffff0000u); }

// ---- K0a: zp = prototypes @ omega^T, plus sq_p partials ------------------
// grid (160, 8), block 128. zp[r,c] = sum_k p[r,k]*om[c,k]
__global__ __launch_bounds__(128)
void k_zp(const float* __restrict__ prot, const float* __restrict__ om,
          float* __restrict__ zp, float* __restrict__ sqp) {
    const int r = blockIdx.x;
    const int c = blockIdx.y * 128 + threadIdx.x;
    __shared__ float prow[F_];
    for (int k = threadIdx.x; k < F_; k += 128) prow[k] = prot[r * F_ + k];
    __syncthreads();
    const float4* o4 = reinterpret_cast<const float4*>(om + (size_t)c * F_);
    float a0 = 0.f, a1 = 0.f, a2 = 0.f, a3 = 0.f;
    for (int k4 = 0; k4 < F_ / 4; ++k4) {
        float4 o = o4[k4];
        a0 = fmaf(prow[k4 * 4 + 0], o.x, a0);
        a1 = fmaf(prow[k4 * 4 + 1], o.y, a1);
        a2 = fmaf(prow[k4 * 4 + 2], o.z, a2);
        a3 = fmaf(prow[k4 * 4 + 3], o.w, a3);
    }
    float v = (a0 + a1) + (a2 + a3);
    zp[(size_t)r * F_ + c] = v;
    // sq_p partial: reduce v*v over the block, one atomic per block
    float s = v * v;
    s += __shfl_xor(s, 1);  s += __shfl_xor(s, 2);  s += __shfl_xor(s, 4);
    s += __shfl_xor(s, 8);  s += __shfl_xor(s, 16); s += __shfl_xor(s, 32);
    __shared__ float wsum[2];
    int lane = threadIdx.x & 63, w = threadIdx.x >> 6;
    if (lane == 0) wsum[w] = s;
    __syncthreads();
    if (threadIdx.x == 0) atomicAdd(&sqp[r], wsum[0] + wsum[1]);
}

// ---- K0b: u = zp @ omega (k-split, atomic accumulate) --------------------
// grid (8, 5, 8), block 128. u[r,c] += sum_{k in chunk} zp[r,k]*om[k,c]
__global__ __launch_bounds__(128)
void k_u(const float* __restrict__ zp, const float* __restrict__ om,
         float* __restrict__ u) {
    const int c  = blockIdx.x * 128 + threadIdx.x;
    const int r0 = blockIdx.y * 32;
    const int kz = blockIdx.z * 128;
    __shared__ __align__(16) float zt[128][36];  // [k][r], padded
    for (int i = threadIdx.x; i < 128 * 32; i += 128) {
        int k = i >> 5, r = i & 31;
        zt[k][r] = zp[(size_t)(r0 + r) * F_ + kz + k];
    }
    __syncthreads();
    float acc[32];
#pragma unroll
    for (int r = 0; r < 32; ++r) acc[r] = 0.f;
    for (int k = 0; k < 128; ++k) {
        float o = om[(size_t)(kz + k) * F_ + c];
        const float4* zr = reinterpret_cast<const float4*>(&zt[k][0]);
#pragma unroll
        for (int r4 = 0; r4 < 8; ++r4) {
            float4 z4 = zr[r4];
            acc[r4 * 4 + 0] = fmaf(z4.x, o, acc[r4 * 4 + 0]);
            acc[r4 * 4 + 1] = fmaf(z4.y, o, acc[r4 * 4 + 1]);
            acc[r4 * 4 + 2] = fmaf(z4.z, o, acc[r4 * 4 + 2]);
            acc[r4 * 4 + 3] = fmaf(z4.w, o, acc[r4 * 4 + 3]);
        }
    }
#pragma unroll
    for (int r = 0; r < 32; ++r) atomicAdd(&u[(size_t)(r0 + r) * F_ + c], acc[r]);
}

// ---- K1: sq_x via bf16 MFMA GEMM z = x @ om^T, fused square-accumulate ---
// grid (64, 8), block 256 (4 waves, 2x2), tile 128x128, K-step 32.
__global__ __launch_bounds__(256)
void k_z_sqx(const float* __restrict__ x, const float* __restrict__ om,
             float* __restrict__ sqx) {
    const int brow = blockIdx.x * 128;
    const int bcol = blockIdx.y * 128;
    __shared__ __align__(16) unsigned short sA[128 * 32];
    __shared__ __align__(16) unsigned short sB[128 * 32];
    const int tid = threadIdx.x;
    const int lane = tid & 63, w = tid >> 6;
    const int wr = (w >> 1) * 64, wc = (w & 1) * 64;
    const int l15 = lane & 15, g = lane >> 4;

    f32x4 acc[4][4] = {};

    for (int k0 = 0; k0 < F_; k0 += 32) {
        __syncthreads();
#pragma unroll
        for (int j = 0; j < 4; ++j) {
            int idx = tid + j * 256;
            int row = idx >> 3, c4 = idx & 7;
            float4 va = *reinterpret_cast<const float4*>(x  + (size_t)(brow + row) * F_ + k0 + c4 * 4);
            float4 vb = *reinterpret_cast<const float4*>(om + (size_t)(bcol + row) * F_ + k0 + c4 * 4);
            int off = (row * 64 + c4 * 8) ^ ((row & 7) << 4);  // XOR swizzle (64B-stride rows)
            *reinterpret_cast<uint2*>(reinterpret_cast<char*>(sA) + off) =
                make_uint2(pk2(va.x, va.y), pk2(va.z, va.w));
            *reinterpret_cast<uint2*>(reinterpret_cast<char*>(sB) + off) =
                make_uint2(pk2(vb.x, vb.y), pk2(vb.z, vb.w));
        }
        __syncthreads();
        short8 a[4], b[4];
#pragma unroll
        for (int m = 0; m < 4; ++m) {
            int row = wr + m * 16 + l15;
            int off = (row * 64 + g * 16) ^ ((row & 7) << 4);
            a[m] = *reinterpret_cast<const short8*>(reinterpret_cast<const char*>(sA) + off);
        }
#pragma unroll
        for (int n = 0; n < 4; ++n) {
            int row = wc + n * 16 + l15;
            int off = (row * 64 + g * 16) ^ ((row & 7) << 4);
            b[n] = *reinterpret_cast<const short8*>(reinterpret_cast<const char*>(sB) + off);
        }
#pragma unroll
        for (int m = 0; m < 4; ++m)
#pragma unroll
            for (int n = 0; n < 4; ++n)
                acc[m][n] = __builtin_amdgcn_mfma_f32_16x16x32_bf16(a[m], b[n], acc[m][n], 0, 0, 0);
    }

    // epilogue: per-row sum of squares across this wave's 64 cols
#pragma unroll
    for (int m = 0; m < 4; ++m) {
#pragma unroll
        for (int j = 0; j < 4; ++j) {
            float s = 0.f;
#pragma unroll
            for (int n = 0; n < 4; ++n) { float v = acc[m][n][j]; s = fmaf(v, v, s); }
            // reduce over the 16 lanes sharing g (cols)
            s += __shfl_xor(s, 1); s += __shfl_xor(s, 2);
            s += __shfl_xor(s, 4); s += __shfl_xor(s, 8);
            if (l15 == 0) atomicAdd(&sqx[brow + wr + m * 16 + g * 4 + j], s);
        }
    }
}

// ---- K2: distances + predictions via split-bf16 MFMA cross term ----------
// grid 256, block 256 (4 waves: wm in {0,1} rows, wn in {0,1} col-halves).
// M-tile 32, N = 160 (10 frags of 16 = 10 classes, PPC = 16), K-step 32.
__global__ __launch_bounds__(256)
void k_dist(const float* __restrict__ x, const float* __restrict__ u,
            const float* __restrict__ sqx, const float* __restrict__ sqp,
            float* __restrict__ dist, float* __restrict__ pred) {
    const int brow = blockIdx.x * 32;
    __shared__ __align__(16) unsigned short sAh[32 * 32], sAl[32 * 32];
    __shared__ __align__(16) unsigned short sBh[160 * 32], sBl[160 * 32];
    __shared__ float cmin[32][10];
    const int tid = threadIdx.x;
    const int lane = tid & 63, w = tid >> 6;
    const int wm = w >> 1, wn = w & 1;
    const int l15 = lane & 15, g = lane >> 4;

    f32x4 acc[5] = {};

    for (int k0 = 0; k0 < F_; k0 += 32) {
        __syncthreads();
        {   // stage A (x tile 32x32), split hi/lo
            int row = tid >> 3, c4 = tid & 7;
            float4 v = *reinterpret_cast<const float4*>(x + (size_t)(brow + row) * F_ + k0 + c4 * 4);
            unsigned h0 = pk2(v.x, v.y), h1 = pk2(v.z, v.w);
            float r0 = v.x - lo_f(h0), r1 = v.y - hi_f(h0);
            float r2 = v.z - lo_f(h1), r3 = v.w - hi_f(h1);
            unsigned q0 = pk2(r0, r1), q1 = pk2(r2, r3);
            int off = (row * 64 + c4 * 8) ^ ((row & 7) << 4);
            *reinterpret_cast<uint2*>(reinterpret_cast<char*>(sAh) + off) = make_uint2(h0, h1);
            *reinterpret_cast<uint2*>(reinterpret_cast<char*>(sAl) + off) = make_uint2(q0, q1);
        }
#pragma unroll
        for (int j = 0; j < 5; ++j) {  // stage B (u tile 160x32), split hi/lo
            int idx = tid + j * 256;
            int row = idx >> 3, c4 = idx & 7;
            float4 v = *reinterpret_cast<const float4*>(u + (size_t)row * F_ + k0 + c4 * 4);
            unsigned h0 = pk2(v.x, v.y), h1 = pk2(v.z, v.w);
            float r0 = v.x - lo_f(h0), r1 = v.y - hi_f(h0);
            float r2 = v.z - lo_f(h1), r3 = v.w - hi_f(h1);
            unsigned q0 = pk2(r0, r1), q1 = pk2(r2, r3);
            int off = (row * 64 + c4 * 8) ^ ((row & 7) << 4);
            *reinterpret_cast<uint2*>(reinterpret_cast<char*>(sBh) + off) = make_uint2(h0, h1);
            *reinterpret_cast<uint2*>(reinterpret_cast<char*>(sBl) + off) = make_uint2(q0, q1);
        }
        __syncthreads();
        int rowA = wm * 16 + l15;
        int offA = (rowA * 64 + g * 16) ^ ((rowA & 7) << 4);
        short8 ah = *reinterpret_cast<const short8*>(reinterpret_cast<const char*>(sAh) + offA);
        short8 al = *reinterpret_cast<const short8*>(reinterpret_cast<const char*>(sAl) + offA);
#pragma unroll
        for (int f = 0; f < 5; ++f) {
            int rowB = wn * 80 + f * 16 + l15;
            int offB = (rowB * 64 + g * 16) ^ ((rowB & 7) << 4);
            short8 bh = *reinterpret_cast<const short8*>(reinterpret_cast<const char*>(sBh) + offB);
            short8 bl = *reinterpret_cast<const short8*>(reinterpret_cast<const char*>(sBl) + offB);
            acc[f] = __builtin_amdgcn_mfma_f32_16x16x32_bf16(ah, bh, acc[f], 0, 0, 0);
            acc[f] = __builtin_amdgcn_mfma_f32_16x16x32_bf16(ah, bl, acc[f], 0, 0, 0);
            acc[f] = __builtin_amdgcn_mfma_f32_16x16x32_bf16(al, bh, acc[f], 0, 0, 0);
            acc[f] = __builtin_amdgcn_mfma_f32_16x16x32_bf16(al, bl, acc[f], 0, 0, 0);
        }
    }

    // epilogue: distances, per-class (16-wide frag) min, argmin
    float sxv[4];
#pragma unroll
    for (int j = 0; j < 4; ++j) sxv[j] = sqx[brow + wm * 16 + g * 4 + j];
#pragma unroll
    for (int f = 0; f < 5; ++f) {
        int col = wn * 80 + f * 16 + l15;
        float sp = sqp[col];
#pragma unroll
        for (int j = 0; j < 4; ++j) {
            float d = sxv[j] + sp - 2.f * acc[f][j];
            dist[(size_t)(brow + wm * 16 + g * 4 + j) * P_ + col] = d;
            float mn = d;
            mn = fminf(mn, __shfl_xor(mn, 1));
            mn = fminf(mn, __shfl_xor(mn, 2));
            mn = fminf(mn, __shfl_xor(mn, 4));
            mn = fminf(mn, __shfl_xor(mn, 8));
            if (l15 == 0) cmin[wm * 16 + g * 4 + j][wn * 5 + f] = mn;
        }
    }
    __syncthreads();
    if (tid < 32) {
        float best = cmin[tid][0];
        int bi = 0;
#pragma unroll
        for (int c = 1; c < C_; ++c) {
            float v = cmin[tid][c];
            if (v < best) { best = v; bi = c; }  // strict '<' => first-min, matches np.argmin
        }
        pred[brow + tid] = (float)bi;
    }
}

// ---- launch --------------------------------------------------------------

extern "C" void kernel_launch(void* const* d_in, const int* in_sizes, int n_in,
                              void* d_out, int out_size, void* d_ws, size_t ws_size,
                              hipStream_t stream) {
    (void)in_sizes; (void)n_in; (void)out_size; (void)ws_size;
    const float* x    = (const float*)d_in[0];
    const float* prot = (const float*)d_in[1];
    const float* om   = (const float*)d_in[2];

    float* wsf = (float*)d_ws;
    float* sqx = wsf;              // 8192
    float* sqp = wsf + 8192;       // 256 (160 used)
    float* zp  = wsf + 8448;       // 163840
    float* u   = wsf + 172288;     // 163840  -> total ~1.35 MB

    float* out  = (float*)d_out;
    float* dist = out;                       // [8192,160]
    float* pred = out + (size_t)B_ * P_;     // [8192] as float

    hipMemsetAsync(sqx, 0, 8192 * sizeof(float), stream);
    hipMemsetAsync(sqp, 0, 256 * sizeof(float), stream);
    hipMemsetAsync(u,   0, (size_t)P_ * F_ * sizeof(float), stream);

    k_zp   <<<dim3(160, 8), 128, 0, stream>>>(prot, om, zp, sqp);
    k_u    <<<dim3(8, 5, 8), 128, 0, stream>>>(zp, om, u);
    k_z_sqx<<<dim3(64, 8),  256, 0, stream>>>(x, om, sqx);
    k_dist <<<dim3(256),    256, 0, stream>>>(x, u, sqx, sqp, dist, pred);
}

// Round 2
// 196.026 us; speedup vs baseline: 1.2177x; 1.2177x over previous
//
#include <hip/hip_runtime.h>
#include <hip/hip_bf16.h>

#define B_ 8192
#define F_ 1024
#define P_ 160
#define C_ 10

typedef __attribute__((ext_vector_type(8))) short short8;
typedef __attribute__((ext_vector_type(4))) float f32x4;

// ---- helpers -------------------------------------------------------------

__device__ inline unsigned pk2(float a, float b) {
    __hip_bfloat162 h = __float22bfloat162_rn(make_float2(a, b));
    return *reinterpret_cast<unsigned*>(&h);
}
__device__ inline float lo_f(unsigned u) { return __uint_as_float(u << 16); }
__device__ inline float hi_f(unsigned u) { return __uint_as_float(u & 0xffff0000u); }

__device__ inline void gload16(const void* g, void* l) {
    __builtin_amdgcn_global_load_lds((const __attribute__((address_space(1))) unsigned*)g,
                                     (__attribute__((address_space(3))) unsigned*)l, 16, 0, 0);
}

// ---- K0a: zp = prototypes @ omega^T, plus sq_p --------------------------
__global__ __launch_bounds__(128)
void k_zp(const float* __restrict__ prot, const float* __restrict__ om,
          float* __restrict__ zp, float* __restrict__ sqp) {
    const int r = blockIdx.x;
    const int c = blockIdx.y * 128 + threadIdx.x;
    __shared__ float prow[F_];
    for (int k = threadIdx.x; k < F_; k += 128) prow[k] = prot[r * F_ + k];
    __syncthreads();
    const float4* o4 = reinterpret_cast<const float4*>(om + (size_t)c * F_);
    float a0 = 0.f, a1 = 0.f, a2 = 0.f, a3 = 0.f;
    for (int k4 = 0; k4 < F_ / 4; ++k4) {
        float4 o = o4[k4];
        a0 = fmaf(prow[k4 * 4 + 0], o.x, a0);
        a1 = fmaf(prow[k4 * 4 + 1], o.y, a1);
        a2 = fmaf(prow[k4 * 4 + 2], o.z, a2);
        a3 = fmaf(prow[k4 * 4 + 3], o.w, a3);
    }
    float v = (a0 + a1) + (a2 + a3);
    zp[(size_t)r * F_ + c] = v;
    float s = v * v;
    s += __shfl_xor(s, 1);  s += __shfl_xor(s, 2);  s += __shfl_xor(s, 4);
    s += __shfl_xor(s, 8);  s += __shfl_xor(s, 16); s += __shfl_xor(s, 32);
    __shared__ float wsum[2];
    int lane = threadIdx.x & 63, w = threadIdx.x >> 6;
    if (lane == 0) wsum[w] = s;
    __syncthreads();
    if (threadIdx.x == 0) atomicAdd(&sqp[r], wsum[0] + wsum[1]);
}

// ---- K0b: u = zp @ omega -------------------------------------------------
__global__ __launch_bounds__(128)
void k_u(const float* __restrict__ zp, const float* __restrict__ om,
         float* __restrict__ u) {
    const int c  = blockIdx.x * 128 + threadIdx.x;
    const int r0 = blockIdx.y * 32;
    const int kz = blockIdx.z * 128;
    __shared__ __align__(16) float zt[128][36];
    for (int i = threadIdx.x; i < 128 * 32; i += 128) {
        int k = i >> 5, r = i & 31;
        zt[k][r] = zp[(size_t)(r0 + r) * F_ + kz + k];
    }
    __syncthreads();
    float acc[32];
#pragma unroll
    for (int r = 0; r < 32; ++r) acc[r] = 0.f;
    for (int k = 0; k < 128; ++k) {
        float o = om[(size_t)(kz + k) * F_ + c];
        const float4* zr = reinterpret_cast<const float4*>(&zt[k][0]);
#pragma unroll
        for (int r4 = 0; r4 < 8; ++r4) {
            float4 z4 = zr[r4];
            acc[r4 * 4 + 0] = fmaf(z4.x, o, acc[r4 * 4 + 0]);
            acc[r4 * 4 + 1] = fmaf(z4.y, o, acc[r4 * 4 + 1]);
            acc[r4 * 4 + 2] = fmaf(z4.z, o, acc[r4 * 4 + 2]);
            acc[r4 * 4 + 3] = fmaf(z4.w, o, acc[r4 * 4 + 3]);
        }
    }
#pragma unroll
    for (int r = 0; r < 32; ++r) atomicAdd(&u[(size_t)(r0 + r) * F_ + c], acc[r]);
}

// ---- K0c: split u into bf16 hi/lo ---------------------------------------
__global__ __launch_bounds__(256)
void k_usplit(const float* __restrict__ u, unsigned short* __restrict__ uh,
              unsigned short* __restrict__ ul) {
    const int b = blockIdx.x, t = threadIdx.x;
    float4 v = *reinterpret_cast<const float4*>(u + (size_t)b * F_ + t * 4);
    unsigned h0 = pk2(v.x, v.y), h1 = pk2(v.z, v.w);
    unsigned q0 = pk2(v.x - lo_f(h0), v.y - hi_f(h0));
    unsigned q1 = pk2(v.z - lo_f(h1), v.w - hi_f(h1));
    *reinterpret_cast<uint2*>(uh + (size_t)b * F_ + t * 4) = make_uint2(h0, h1);
    *reinterpret_cast<uint2*>(ul + (size_t)b * F_ + t * 4) = make_uint2(q0, q1);
}

// ---- pre-convert x / om to PRE-SWIZZLED bf16 tiled layout ----------------
// layout: [row_block][k_tile(32)][128x32 tile, byte = (r*64 + k8*16) ^ ((r&7)<<4)]
__global__ __launch_bounds__(256)
void k_cvt_sw(const float* __restrict__ src, unsigned short* __restrict__ dst) {
    const int c = blockIdx.x * 256 + threadIdx.x;   // one 16B chunk (8 elems)
    const int rg = c >> 7, kg = c & 127;
    const int t = kg >> 2, k8 = kg & 3;
    const float4* s4 = reinterpret_cast<const float4*>(src + (size_t)rg * F_ + t * 32 + k8 * 8);
    float4 v0 = s4[0], v1 = s4[1];
    uint4 o;
    o.x = pk2(v0.x, v0.y); o.y = pk2(v0.z, v0.w);
    o.z = pk2(v1.x, v1.y); o.w = pk2(v1.z, v1.w);
    const int rb = rg >> 7, r = rg & 127;
    size_t base = ((size_t)(rb * 32 + t)) * 8192;
    int off = (r * 64 + k8 * 16) ^ ((r & 7) << 4);
    *reinterpret_cast<uint4*>(reinterpret_cast<char*>(dst) + base + off) = o;
}

// ---- K1 fast: sq_x via bf16 MFMA GEMM with global_load_lds ---------------
// grid (64, 8), block 256 (4 waves 2x2), tile 128x128, BK=32.
__global__ __launch_bounds__(256)
void k_z_sqx2(const unsigned short* __restrict__ xh, const unsigned short* __restrict__ omh,
              float* __restrict__ sqx) {
    const int bx = blockIdx.x, by = blockIdx.y;
    __shared__ __align__(16) unsigned short sA[128 * 32];
    __shared__ __align__(16) unsigned short sB[128 * 32];
    const int tid = threadIdx.x;
    const int lane = tid & 63, w = tid >> 6;
    const int wr = (w >> 1) * 64, wc = (w & 1) * 64;
    const int l15 = lane & 15, g = lane >> 4;

    f32x4 acc[4][4] = {};
    const char* xb = reinterpret_cast<const char*>(xh) + (size_t)bx * 32 * 8192;
    const char* ob = reinterpret_cast<const char*>(omh) + (size_t)by * 32 * 8192;
    char* sAc = reinterpret_cast<char*>(sA);
    char* sBc = reinterpret_cast<char*>(sB);

    for (int t = 0; t < 32; ++t) {
        __syncthreads();
        gload16(xb + (size_t)t * 8192 + tid * 16,        sAc + tid * 16);
        gload16(xb + (size_t)t * 8192 + 4096 + tid * 16, sAc + 4096 + tid * 16);
        gload16(ob + (size_t)t * 8192 + tid * 16,        sBc + tid * 16);
        gload16(ob + (size_t)t * 8192 + 4096 + tid * 16, sBc + 4096 + tid * 16);
        __syncthreads();
        short8 a[4], b[4];
#pragma unroll
        for (int m = 0; m < 4; ++m) {
            int row = wr + m * 16 + l15;
            int off = (row * 64 + g * 16) ^ ((row & 7) << 4);
            a[m] = *reinterpret_cast<const short8*>(sAc + off);
        }
#pragma unroll
        for (int n = 0; n < 4; ++n) {
            int row = wc + n * 16 + l15;
            int off = (row * 64 + g * 16) ^ ((row & 7) << 4);
            b[n] = *reinterpret_cast<const short8*>(sBc + off);
        }
#pragma unroll
        for (int m = 0; m < 4; ++m)
#pragma unroll
            for (int n = 0; n < 4; ++n)
                acc[m][n] = __builtin_amdgcn_mfma_f32_16x16x32_bf16(a[m], b[n], acc[m][n], 0, 0, 0);
    }
#pragma unroll
    for (int m = 0; m < 4; ++m) {
#pragma unroll
        for (int j = 0; j < 4; ++j) {
            float s = 0.f;
#pragma unroll
            for (int n = 0; n < 4; ++n) { float v = acc[m][n][j]; s = fmaf(v, v, s); }
            s += __shfl_xor(s, 1); s += __shfl_xor(s, 2);
            s += __shfl_xor(s, 4); s += __shfl_xor(s, 8);
            if (l15 == 0) atomicAdd(&sqx[bx * 128 + wr + m * 16 + g * 4 + j], s);
        }
    }
}

// ---- K1 fallback (R0 version): inline convert, used if ws too small ------
__global__ __launch_bounds__(256)
void k_z_sqx(const float* __restrict__ x, const float* __restrict__ om,
             float* __restrict__ sqx) {
    const int brow = blockIdx.x * 128;
    const int bcol = blockIdx.y * 128;
    __shared__ __align__(16) unsigned short sA[128 * 32];
    __shared__ __align__(16) unsigned short sB[128 * 32];
    const int tid = threadIdx.x;
    const int lane = tid & 63, w = tid >> 6;
    const int wr = (w >> 1) * 64, wc = (w & 1) * 64;
    const int l15 = lane & 15, g = lane >> 4;
    f32x4 acc[4][4] = {};
    for (int k0 = 0; k0 < F_; k0 += 32) {
        __syncthreads();
#pragma unroll
        for (int j = 0; j < 4; ++j) {
            int idx = tid + j * 256;
            int row = idx >> 3, c4 = idx & 7;
            float4 va = *reinterpret_cast<const float4*>(x  + (size_t)(brow + row) * F_ + k0 + c4 * 4);
            float4 vb = *reinterpret_cast<const float4*>(om + (size_t)(bcol + row) * F_ + k0 + c4 * 4);
            int off = (row * 64 + c4 * 8) ^ ((row & 7) << 4);
            *reinterpret_cast<uint2*>(reinterpret_cast<char*>(sA) + off) =
                make_uint2(pk2(va.x, va.y), pk2(va.z, va.w));
            *reinterpret_cast<uint2*>(reinterpret_cast<char*>(sB) + off) =
                make_uint2(pk2(vb.x, vb.y), pk2(vb.z, vb.w));
        }
        __syncthreads();
        short8 a[4], b[4];
#pragma unroll
        for (int m = 0; m < 4; ++m) {
            int row = wr + m * 16 + l15;
            int off = (row * 64 + g * 16) ^ ((row & 7) << 4);
            a[m] = *reinterpret_cast<const short8*>(reinterpret_cast<const char*>(sA) + off);
        }
#pragma unroll
        for (int n = 0; n < 4; ++n) {
            int row = wc + n * 16 + l15;
            int off = (row * 64 + g * 16) ^ ((row & 7) << 4);
            b[n] = *reinterpret_cast<const short8*>(reinterpret_cast<const char*>(sB) + off);
        }
#pragma unroll
        for (int m = 0; m < 4; ++m)
#pragma unroll
            for (int n = 0; n < 4; ++n)
                acc[m][n] = __builtin_amdgcn_mfma_f32_16x16x32_bf16(a[m], b[n], acc[m][n], 0, 0, 0);
    }
#pragma unroll
    for (int m = 0; m < 4; ++m) {
#pragma unroll
        for (int j = 0; j < 4; ++j) {
            float s = 0.f;
#pragma unroll
            for (int n = 0; n < 4; ++n) { float v = acc[m][n][j]; s = fmaf(v, v, s); }
            s += __shfl_xor(s, 1); s += __shfl_xor(s, 2);
            s += __shfl_xor(s, 4); s += __shfl_xor(s, 8);
            if (l15 == 0) atomicAdd(&sqx[brow + wr + m * 16 + g * 4 + j], s);
        }
    }
}

// ---- K2: distances + predictions, barrier-free K-split -------------------
// grid 512, block 256 (4 waves, each owns K-quarter 256). M-tile 16, N=160.
__global__ __launch_bounds__(256)
void k_dist2(const float* __restrict__ x, const unsigned short* __restrict__ uh,
             const unsigned short* __restrict__ ul, const float* __restrict__ sqx,
             const float* __restrict__ sqp, float* __restrict__ dist,
             float* __restrict__ pred) {
    const int brow = blockIdx.x * 16;
    const int tid = threadIdx.x, lane = tid & 63, w = tid >> 6;
    const int l15 = lane & 15, g = lane >> 4;
    __shared__ float red[4][10][16][16];

    f32x4 acc[10] = {};
    const float* xp = x + (size_t)(brow + l15) * F_ + w * 256 + g * 8;
    const unsigned short* buh = uh + (size_t)l15 * F_ + w * 256 + g * 8;
    const unsigned short* bul = ul + (size_t)l15 * F_ + w * 256 + g * 8;

#pragma unroll 2
    for (int ks = 0; ks < 8; ++ks) {
        float4 v0 = *reinterpret_cast<const float4*>(xp + ks * 32);
        float4 v1 = *reinterpret_cast<const float4*>(xp + ks * 32 + 4);
        union { unsigned u[4]; short8 s; } cva, cvl;
        cva.u[0] = pk2(v0.x, v0.y); cva.u[1] = pk2(v0.z, v0.w);
        cva.u[2] = pk2(v1.x, v1.y); cva.u[3] = pk2(v1.z, v1.w);
        cvl.u[0] = pk2(v0.x - lo_f(cva.u[0]), v0.y - hi_f(cva.u[0]));
        cvl.u[1] = pk2(v0.z - lo_f(cva.u[1]), v0.w - hi_f(cva.u[1]));
        cvl.u[2] = pk2(v1.x - lo_f(cva.u[2]), v1.y - hi_f(cva.u[2]));
        cvl.u[3] = pk2(v1.z - lo_f(cva.u[3]), v1.w - hi_f(cva.u[3]));
        short8 ah = cva.s, al = cvl.s;
#pragma unroll
        for (int f = 0; f < 10; ++f) {
            short8 bh = *reinterpret_cast<const short8*>(buh + (size_t)f * 16 * F_ + ks * 32);
            short8 bl = *reinterpret_cast<const short8*>(bul + (size_t)f * 16 * F_ + ks * 32);
            acc[f] = __builtin_amdgcn_mfma_f32_16x16x32_bf16(ah, bh, acc[f], 0, 0, 0);
            acc[f] = __builtin_amdgcn_mfma_f32_16x16x32_bf16(al, bh, acc[f], 0, 0, 0);
            acc[f] = __builtin_amdgcn_mfma_f32_16x16x32_bf16(ah, bl, acc[f], 0, 0, 0);
        }
    }

#pragma unroll
    for (int f = 0; f < 10; ++f)
#pragma unroll
        for (int j = 0; j < 4; ++j) red[w][f][g * 4 + j][l15] = acc[f][j];
    __syncthreads();

    const int m = tid >> 4, n = tid & 15;
    const int row = brow + m;
    float sx = sqx[row];
    float best = 3.4e38f; int bi = 0;
#pragma unroll
    for (int f = 0; f < 10; ++f) {
        float d = red[0][f][m][n] + red[1][f][m][n] + red[2][f][m][n] + red[3][f][m][n];
        float dv = sx + sqp[f * 16 + n] - 2.f * d;
        dist[(size_t)row * P_ + f * 16 + n] = dv;
        float mn = dv;
        mn = fminf(mn, __shfl_xor(mn, 1));
        mn = fminf(mn, __shfl_xor(mn, 2));
        mn = fminf(mn, __shfl_xor(mn, 4));
        mn = fminf(mn, __shfl_xor(mn, 8));
        if (mn < best) { best = mn; bi = f; }   // strict '<' => first min, np.argmin
    }
    if (n == 0) pred[row] = (float)bi;
}

// ---- launch --------------------------------------------------------------

extern "C" void kernel_launch(void* const* d_in, const int* in_sizes, int n_in,
                              void* d_out, int out_size, void* d_ws, size_t ws_size,
                              hipStream_t stream) {
    (void)in_sizes; (void)n_in; (void)out_size;
    const float* x    = (const float*)d_in[0];
    const float* prot = (const float*)d_in[1];
    const float* om   = (const float*)d_in[2];

    float* wsf = (float*)d_ws;
    float* sqx = wsf;                                   // 8192 f32
    float* sqp = wsf + 8192;                            // 256 f32
    float* u   = wsf + 172288;                          // 160*1024 f32
    float* zp  = wsf + 8448;                            // 160*1024 f32 (dead after k_u)
    unsigned short* uh = (unsigned short*)(wsf + 8448); // overlays zp: 160*1024 bf16
    unsigned short* ul = uh + 163840;                   // 160*1024 bf16
    unsigned short* omh = (unsigned short*)(wsf + 336128);            // 2 MB
    unsigned short* xh  = (unsigned short*)(wsf + 336128 + 524288);   // 16 MB

    float* out  = (float*)d_out;
    float* dist = out;
    float* pred = out + (size_t)B_ * P_;

    const bool big = ws_size >= (size_t)24 * 1024 * 1024;

    hipMemsetAsync(sqx, 0, 8192 * sizeof(float), stream);
    hipMemsetAsync(sqp, 0, 256 * sizeof(float), stream);
    hipMemsetAsync(u,   0, (size_t)P_ * F_ * sizeof(float), stream);

    k_zp    <<<dim3(160, 8), 128, 0, stream>>>(prot, om, zp, sqp);
    k_u     <<<dim3(8, 5, 8), 128, 0, stream>>>(zp, om, u);
    k_usplit<<<160, 256, 0, stream>>>(u, uh, ul);

    if (big) {
        k_cvt_sw<<<4096, 256, 0, stream>>>(x, xh);    // 8192*128 chunks
        k_cvt_sw<<<512, 256, 0, stream>>>(om, omh);   // 1024*128 chunks
        k_z_sqx2<<<dim3(64, 8), 256, 0, stream>>>(xh, omh, sqx);
    } else {
        k_z_sqx<<<dim3(64, 8), 256, 0, stream>>>(x, om, sqx);
    }
    k_dist2<<<512, 256, 0, stream>>>(x, uh, ul, sqx, sqp, dist, pred);
}

// Round 3
// 158.596 us; speedup vs baseline: 1.5051x; 1.2360x over previous
//
#include <hip/hip_runtime.h>
#include <hip/hip_bf16.h>

#define B_ 8192
#define F_ 1024
#define P_ 160
#define C_ 10

typedef __attribute__((ext_vector_type(8))) short short8;
typedef __attribute__((ext_vector_type(4))) float f32x4;

// ---- helpers -------------------------------------------------------------

__device__ inline unsigned pk2(float a, float b) {
    __hip_bfloat162 h = __float22bfloat162_rn(make_float2(a, b));
    return *reinterpret_cast<unsigned*>(&h);
}
__device__ inline float lo_f(unsigned u) { return __uint_as_float(u << 16); }
__device__ inline float hi_f(unsigned u) { return __uint_as_float(u & 0xffff0000u); }

__device__ inline void gload16(const void* g, void* l) {
    __builtin_amdgcn_global_load_lds((const __attribute__((address_space(1))) unsigned*)g,
                                     (__attribute__((address_space(3))) unsigned*)l, 16, 0, 0);
}

// ---- K0a: zp = prot @ om^T via split-bf16 MFMA, fused sqp ----------------
// grid 64 (n-tiles of 16 cols), block 256 = 4 waves, wave w owns K in
// [w*256, w*256+256). Barrier-free K-loop; LDS reduce epilogue.
__global__ __launch_bounds__(256)
void k_proj(const float* __restrict__ prot, const float* __restrict__ om,
            float* __restrict__ zp, float* __restrict__ sqp) {
    const int n0 = blockIdx.x * 16;
    const int tid = threadIdx.x, lane = tid & 63, w = tid >> 6;
    const int l15 = lane & 15, g = lane >> 4;
    __shared__ float red[4][10][16][16];  // 40 KB

    f32x4 acc[10] = {};
    const float* op = om   + (size_t)(n0 + l15) * F_ + w * 256 + g * 8;
    const float* pp = prot + (size_t)l15 * F_ + w * 256 + g * 8;

#pragma unroll 2
    for (int ks = 0; ks < 8; ++ks) {
        float4 b0 = *reinterpret_cast<const float4*>(op + ks * 32);
        float4 b1 = *reinterpret_cast<const float4*>(op + ks * 32 + 4);
        union { unsigned u[4]; short8 s; } cbh, cbl;
        cbh.u[0] = pk2(b0.x, b0.y); cbh.u[1] = pk2(b0.z, b0.w);
        cbh.u[2] = pk2(b1.x, b1.y); cbh.u[3] = pk2(b1.z, b1.w);
        cbl.u[0] = pk2(b0.x - lo_f(cbh.u[0]), b0.y - hi_f(cbh.u[0]));
        cbl.u[1] = pk2(b0.z - lo_f(cbh.u[1]), b0.w - hi_f(cbh.u[1]));
        cbl.u[2] = pk2(b1.x - lo_f(cbh.u[2]), b1.y - hi_f(cbh.u[2]));
        cbl.u[3] = pk2(b1.z - lo_f(cbh.u[3]), b1.w - hi_f(cbh.u[3]));
        short8 bh = cbh.s, bl = cbl.s;
#pragma unroll
        for (int f = 0; f < 10; ++f) {
            float4 a0 = *reinterpret_cast<const float4*>(pp + (size_t)f * 16 * F_ + ks * 32);
            float4 a1 = *reinterpret_cast<const float4*>(pp + (size_t)f * 16 * F_ + ks * 32 + 4);
            union { unsigned u[4]; short8 s; } cah, cal;
            cah.u[0] = pk2(a0.x, a0.y); cah.u[1] = pk2(a0.z, a0.w);
            cah.u[2] = pk2(a1.x, a1.y); cah.u[3] = pk2(a1.z, a1.w);
            cal.u[0] = pk2(a0.x - lo_f(cah.u[0]), a0.y - hi_f(cah.u[0]));
            cal.u[1] = pk2(a0.z - lo_f(cah.u[1]), a0.w - hi_f(cah.u[1]));
            cal.u[2] = pk2(a1.x - lo_f(cah.u[2]), a1.y - hi_f(cah.u[2]));
            cal.u[3] = pk2(a1.z - lo_f(cah.u[3]), a1.w - hi_f(cah.u[3]));
            acc[f] = __builtin_amdgcn_mfma_f32_16x16x32_bf16(cah.s, bh, acc[f], 0, 0, 0);
            acc[f] = __builtin_amdgcn_mfma_f32_16x16x32_bf16(cal.s, bh, acc[f], 0, 0, 0);
            acc[f] = __builtin_amdgcn_mfma_f32_16x16x32_bf16(cah.s, bl, acc[f], 0, 0, 0);
        }
    }
#pragma unroll
    for (int f = 0; f < 10; ++f)
#pragma unroll
        for (int j = 0; j < 4; ++j) red[w][f][g * 4 + j][l15] = acc[f][j];
    __syncthreads();
    if (tid < 160) {
        const int f = tid >> 4, m = tid & 15;
        float s = 0.f;
#pragma unroll
        for (int n = 0; n < 16; ++n) {
            float v = red[0][f][m][n] + red[1][f][m][n] + red[2][f][m][n] + red[3][f][m][n];
            zp[(size_t)tid * F_ + n0 + n] = v;
            s = fmaf(v, v, s);
        }
        atomicAdd(&sqp[tid], s);
    }
}

// ---- K0b: u = zp @ omega -------------------------------------------------
__global__ __launch_bounds__(128)
void k_u(const float* __restrict__ zp, const float* __restrict__ om,
         float* __restrict__ u) {
    const int c  = blockIdx.x * 128 + threadIdx.x;
    const int r0 = blockIdx.y * 32;
    const int kz = blockIdx.z * 128;
    __shared__ __align__(16) float zt[128][36];
    for (int i = threadIdx.x; i < 128 * 32; i += 128) {
        int k = i >> 5, r = i & 31;
        zt[k][r] = zp[(size_t)(r0 + r) * F_ + kz + k];
    }
    __syncthreads();
    float acc[32];
#pragma unroll
    for (int r = 0; r < 32; ++r) acc[r] = 0.f;
    for (int k = 0; k < 128; ++k) {
        float o = om[(size_t)(kz + k) * F_ + c];
        const float4* zr = reinterpret_cast<const float4*>(&zt[k][0]);
#pragma unroll
        for (int r4 = 0; r4 < 8; ++r4) {
            float4 z4 = zr[r4];
            acc[r4 * 4 + 0] = fmaf(z4.x, o, acc[r4 * 4 + 0]);
            acc[r4 * 4 + 1] = fmaf(z4.y, o, acc[r4 * 4 + 1]);
            acc[r4 * 4 + 2] = fmaf(z4.z, o, acc[r4 * 4 + 2]);
            acc[r4 * 4 + 3] = fmaf(z4.w, o, acc[r4 * 4 + 3]);
        }
    }
#pragma unroll
    for (int r = 0; r < 32; ++r) atomicAdd(&u[(size_t)(r0 + r) * F_ + c], acc[r]);
}

// ---- K0c: split u into bf16 hi/lo ---------------------------------------
__global__ __launch_bounds__(256)
void k_usplit(const float* __restrict__ u, unsigned short* __restrict__ uh,
              unsigned short* __restrict__ ul) {
    const int b = blockIdx.x, t = threadIdx.x;
    float4 v = *reinterpret_cast<const float4*>(u + (size_t)b * F_ + t * 4);
    unsigned h0 = pk2(v.x, v.y), h1 = pk2(v.z, v.w);
    unsigned q0 = pk2(v.x - lo_f(h0), v.y - hi_f(h0));
    unsigned q1 = pk2(v.z - lo_f(h1), v.w - hi_f(h1));
    *reinterpret_cast<uint2*>(uh + (size_t)b * F_ + t * 4) = make_uint2(h0, h1);
    *reinterpret_cast<uint2*>(ul + (size_t)b * F_ + t * 4) = make_uint2(q0, q1);
}

// ---- pre-convert x / om to PRE-SWIZZLED bf16 tiled layout ----------------
__global__ __launch_bounds__(256)
void k_cvt_sw(const float* __restrict__ src, unsigned short* __restrict__ dst) {
    const int c = blockIdx.x * 256 + threadIdx.x;
    const int rg = c >> 7, kg = c & 127;
    const int t = kg >> 2, k8 = kg & 3;
    const float4* s4 = reinterpret_cast<const float4*>(src + (size_t)rg * F_ + t * 32 + k8 * 8);
    float4 v0 = s4[0], v1 = s4[1];
    uint4 o;
    o.x = pk2(v0.x, v0.y); o.y = pk2(v0.z, v0.w);
    o.z = pk2(v1.x, v1.y); o.w = pk2(v1.z, v1.w);
    const int rb = rg >> 7, r = rg & 127;
    size_t base = ((size_t)(rb * 32 + t)) * 8192;
    int off = (r * 64 + k8 * 16) ^ ((r & 7) << 4);
    *reinterpret_cast<uint4*>(reinterpret_cast<char*>(dst) + base + off) = o;
}

// ---- K1 fast: sq_x via bf16 MFMA GEMM with global_load_lds ---------------
__global__ __launch_bounds__(256)
void k_z_sqx2(const unsigned short* __restrict__ xh, const unsigned short* __restrict__ omh,
              float* __restrict__ sqx) {
    const int bx = blockIdx.x, by = blockIdx.y;
    __shared__ __align__(16) unsigned short sA[128 * 32];
    __shared__ __align__(16) unsigned short sB[128 * 32];
    const int tid = threadIdx.x;
    const int lane = tid & 63, w = tid >> 6;
    const int wr = (w >> 1) * 64, wc = (w & 1) * 64;
    const int l15 = lane & 15, g = lane >> 4;

    f32x4 acc[4][4] = {};
    const char* xb = reinterpret_cast<const char*>(xh) + (size_t)bx * 32 * 8192;
    const char* ob = reinterpret_cast<const char*>(omh) + (size_t)by * 32 * 8192;
    char* sAc = reinterpret_cast<char*>(sA);
    char* sBc = reinterpret_cast<char*>(sB);

    for (int t = 0; t < 32; ++t) {
        __syncthreads();
        gload16(xb + (size_t)t * 8192 + tid * 16,        sAc + tid * 16);
        gload16(xb + (size_t)t * 8192 + 4096 + tid * 16, sAc + 4096 + tid * 16);
        gload16(ob + (size_t)t * 8192 + tid * 16,        sBc + tid * 16);
        gload16(ob + (size_t)t * 8192 + 4096 + tid * 16, sBc + 4096 + tid * 16);
        __syncthreads();
        short8 a[4], b[4];
#pragma unroll
        for (int m = 0; m < 4; ++m) {
            int row = wr + m * 16 + l15;
            int off = (row * 64 + g * 16) ^ ((row & 7) << 4);
            a[m] = *reinterpret_cast<const short8*>(sAc + off);
        }
#pragma unroll
        for (int n = 0; n < 4; ++n) {
            int row = wc + n * 16 + l15;
            int off = (row * 64 + g * 16) ^ ((row & 7) << 4);
            b[n] = *reinterpret_cast<const short8*>(sBc + off);
        }
#pragma unroll
        for (int m = 0; m < 4; ++m)
#pragma unroll
            for (int n = 0; n < 4; ++n)
                acc[m][n] = __builtin_amdgcn_mfma_f32_16x16x32_bf16(a[m], b[n], acc[m][n], 0, 0, 0);
    }
#pragma unroll
    for (int m = 0; m < 4; ++m) {
#pragma unroll
        for (int j = 0; j < 4; ++j) {
            float s = 0.f;
#pragma unroll
            for (int n = 0; n < 4; ++n) { float v = acc[m][n][j]; s = fmaf(v, v, s); }
            s += __shfl_xor(s, 1); s += __shfl_xor(s, 2);
            s += __shfl_xor(s, 4); s += __shfl_xor(s, 8);
            if (l15 == 0) atomicAdd(&sqx[bx * 128 + wr + m * 16 + g * 4 + j], s);
        }
    }
}

// ---- K1 fallback: inline convert (used if ws too small) ------------------
__global__ __launch_bounds__(256)
void k_z_sqx(const float* __restrict__ x, const float* __restrict__ om,
             float* __restrict__ sqx) {
    const int brow = blockIdx.x * 128;
    const int bcol = blockIdx.y * 128;
    __shared__ __align__(16) unsigned short sA[128 * 32];
    __shared__ __align__(16) unsigned short sB[128 * 32];
    const int tid = threadIdx.x;
    const int lane = tid & 63, w = tid >> 6;
    const int wr = (w >> 1) * 64, wc = (w & 1) * 64;
    const int l15 = lane & 15, g = lane >> 4;
    f32x4 acc[4][4] = {};
    for (int k0 = 0; k0 < F_; k0 += 32) {
        __syncthreads();
#pragma unroll
        for (int j = 0; j < 4; ++j) {
            int idx = tid + j * 256;
            int row = idx >> 3, c4 = idx & 7;
            float4 va = *reinterpret_cast<const float4*>(x  + (size_t)(brow + row) * F_ + k0 + c4 * 4);
            float4 vb = *reinterpret_cast<const float4*>(om + (size_t)(bcol + row) * F_ + k0 + c4 * 4);
            int off = (row * 64 + c4 * 8) ^ ((row & 7) << 4);
            *reinterpret_cast<uint2*>(reinterpret_cast<char*>(sA) + off) =
                make_uint2(pk2(va.x, va.y), pk2(va.z, va.w));
            *reinterpret_cast<uint2*>(reinterpret_cast<char*>(sB) + off) =
                make_uint2(pk2(vb.x, vb.y), pk2(vb.z, vb.w));
        }
        __syncthreads();
        short8 a[4], b[4];
#pragma unroll
        for (int m = 0; m < 4; ++m) {
            int row = wr + m * 16 + l15;
            int off = (row * 64 + g * 16) ^ ((row & 7) << 4);
            a[m] = *reinterpret_cast<const short8*>(reinterpret_cast<const char*>(sA) + off);
        }
#pragma unroll
        for (int n = 0; n < 4; ++n) {
            int row = wc + n * 16 + l15;
            int off = (row * 64 + g * 16) ^ ((row & 7) << 4);
            b[n] = *reinterpret_cast<const short8*>(reinterpret_cast<const char*>(sB) + off);
        }
#pragma unroll
        for (int m = 0; m < 4; ++m)
#pragma unroll
            for (int n = 0; n < 4; ++n)
                acc[m][n] = __builtin_amdgcn_mfma_f32_16x16x32_bf16(a[m], b[n], acc[m][n], 0, 0, 0);
    }
#pragma unroll
    for (int m = 0; m < 4; ++m) {
#pragma unroll
        for (int j = 0; j < 4; ++j) {
            float s = 0.f;
#pragma unroll
            for (int n = 0; n < 4; ++n) { float v = acc[m][n][j]; s = fmaf(v, v, s); }
            s += __shfl_xor(s, 1); s += __shfl_xor(s, 2);
            s += __shfl_xor(s, 4); s += __shfl_xor(s, 8);
            if (l15 == 0) atomicAdd(&sqx[brow + wr + m * 16 + g * 4 + j], s);
        }
    }
}

// ---- K2: distances + predictions, barrier-free K-split -------------------
__global__ __launch_bounds__(256)
void k_dist2(const float* __restrict__ x, const unsigned short* __restrict__ uh,
             const unsigned short* __restrict__ ul, const float* __restrict__ sqx,
             const float* __restrict__ sqp, float* __restrict__ dist,
             float* __restrict__ pred) {
    const int brow = blockIdx.x * 16;
    const int tid = threadIdx.x, lane = tid & 63, w = tid >> 6;
    const int l15 = lane & 15, g = lane >> 4;
    __shared__ float red[4][10][16][16];

    f32x4 acc[10] = {};
    const float* xp = x + (size_t)(brow + l15) * F_ + w * 256 + g * 8;
    const unsigned short* buh = uh + (size_t)l15 * F_ + w * 256 + g * 8;
    const unsigned short* bul = ul + (size_t)l15 * F_ + w * 256 + g * 8;

#pragma unroll 2
    for (int ks = 0; ks < 8; ++ks) {
        float4 v0 = *reinterpret_cast<const float4*>(xp + ks * 32);
        float4 v1 = *reinterpret_cast<const float4*>(xp + ks * 32 + 4);
        union { unsigned u[4]; short8 s; } cva, cvl;
        cva.u[0] = pk2(v0.x, v0.y); cva.u[1] = pk2(v0.z, v0.w);
        cva.u[2] = pk2(v1.x, v1.y); cva.u[3] = pk2(v1.z, v1.w);
        cvl.u[0] = pk2(v0.x - lo_f(cva.u[0]), v0.y - hi_f(cva.u[0]));
        cvl.u[1] = pk2(v0.z - lo_f(cva.u[1]), v0.w - hi_f(cva.u[1]));
        cvl.u[2] = pk2(v1.x - lo_f(cva.u[2]), v1.y - hi_f(cva.u[2]));
        cvl.u[3] = pk2(v1.z - lo_f(cva.u[3]), v1.w - hi_f(cva.u[3]));
        short8 ah = cva.s, al = cvl.s;
#pragma unroll
        for (int f = 0; f < 10; ++f) {
            short8 bh = *reinterpret_cast<const short8*>(buh + (size_t)f * 16 * F_ + ks * 32);
            short8 bl = *reinterpret_cast<const short8*>(bul + (size_t)f * 16 * F_ + ks * 32);
            acc[f] = __builtin_amdgcn_mfma_f32_16x16x32_bf16(ah, bh, acc[f], 0, 0, 0);
            acc[f] = __builtin_amdgcn_mfma_f32_16x16x32_bf16(al, bh, acc[f], 0, 0, 0);
            acc[f] = __builtin_amdgcn_mfma_f32_16x16x32_bf16(ah, bl, acc[f], 0, 0, 0);
        }
    }

#pragma unroll
    for (int f = 0; f < 10; ++f)
#pragma unroll
        for (int j = 0; j < 4; ++j) red[w][f][g * 4 + j][l15] = acc[f][j];
    __syncthreads();

    const int m = tid >> 4, n = tid & 15;
    const int row = brow + m;
    float sx = sqx[row];
    float best = 3.4e38f; int bi = 0;
#pragma unroll
    for (int f = 0; f < 10; ++f) {
        float d = red[0][f][m][n] + red[1][f][m][n] + red[2][f][m][n] + red[3][f][m][n];
        float dv = sx + sqp[f * 16 + n] - 2.f * d;
        dist[(size_t)row * P_ + f * 16 + n] = dv;
        float mn = dv;
        mn = fminf(mn, __shfl_xor(mn, 1));
        mn = fminf(mn, __shfl_xor(mn, 2));
        mn = fminf(mn, __shfl_xor(mn, 4));
        mn = fminf(mn, __shfl_xor(mn, 8));
        if (mn < best) { best = mn; bi = f; }
    }
    if (n == 0) pred[row] = (float)bi;
}

// ---- launch --------------------------------------------------------------

extern "C" void kernel_launch(void* const* d_in, const int* in_sizes, int n_in,
                              void* d_out, int out_size, void* d_ws, size_t ws_size,
                              hipStream_t stream) {
    (void)in_sizes; (void)n_in; (void)out_size;
    const float* x    = (const float*)d_in[0];
    const float* prot = (const float*)d_in[1];
    const float* om   = (const float*)d_in[2];

    float* wsf = (float*)d_ws;
    float* sqx = wsf;                                   // 8192 f32
    float* sqp = wsf + 8192;                            // 256 f32
    float* zp  = wsf + 8448;                            // 160*1024 f32 (dead after k_u)
    float* u   = wsf + 172288;                          // 160*1024 f32
    unsigned short* uh = (unsigned short*)(wsf + 8448); // overlays zp
    unsigned short* ul = uh + 163840;
    unsigned short* omh = (unsigned short*)(wsf + 336128);            // 2 MB
    unsigned short* xh  = (unsigned short*)(wsf + 336128 + 524288);   // 16 MB

    float* out  = (float*)d_out;
    float* dist = out;
    float* pred = out + (size_t)B_ * P_;

    const bool big = ws_size >= (size_t)24 * 1024 * 1024;

    hipMemsetAsync(sqx, 0, 8192 * sizeof(float), stream);
    hipMemsetAsync(sqp, 0, 256 * sizeof(float), stream);
    hipMemsetAsync(u,   0, (size_t)P_ * F_ * sizeof(float), stream);

    k_proj  <<<64, 256, 0, stream>>>(prot, om, zp, sqp);
    k_u     <<<dim3(8, 5, 8), 128, 0, stream>>>(zp, om, u);
    k_usplit<<<160, 256, 0, stream>>>(u, uh, ul);

    if (big) {
        k_cvt_sw<<<4096, 256, 0, stream>>>(x, xh);
        k_cvt_sw<<<512, 256, 0, stream>>>(om, omh);
        k_z_sqx2<<<dim3(64, 8), 256, 0, stream>>>(xh, omh, sqx);
    } else {
        k_z_sqx<<<dim3(64, 8), 256, 0, stream>>>(x, om, sqx);
    }
    k_dist2<<<512, 256, 0, stream>>>(x, uh, ul, sqx, sqp, dist, pred);
}

// Round 4
// 134.088 us; speedup vs baseline: 1.7802x; 1.1828x over previous
//
#include <hip/hip_runtime.h>
#include <hip/hip_bf16.h>

#define B_ 8192
#define F_ 1024
#define P_ 160
#define C_ 10

typedef __attribute__((ext_vector_type(8))) short short8;
typedef __attribute__((ext_vector_type(4))) float f32x4;
typedef unsigned short ushort_t;

// ---- helpers -------------------------------------------------------------

__device__ inline unsigned pk2(float a, float b) {
    __hip_bfloat162 h = __float22bfloat162_rn(make_float2(a, b));
    return *reinterpret_cast<unsigned*>(&h);
}
__device__ inline float lo_f(unsigned u) { return __uint_as_float(u << 16); }
__device__ inline float hi_f(unsigned u) { return __uint_as_float(u & 0xffff0000u); }

__device__ inline void gload16(const void* g, void* l) {
    __builtin_amdgcn_global_load_lds((const __attribute__((address_space(1))) unsigned*)g,
                                     (__attribute__((address_space(3))) unsigned*)l, 16, 0, 0);
}

// ---- k_prep1: all operand conversions in one pass ------------------------
// blocks 0..255: om 64x64 tiles -> omh_r/oml_r (row-major split), omTh/omTl
// (transposed split), omh_sw (pre-swizzled hi for k_z_sqx2 B).
// blocks 256..265: prot -> phl/pll.
__global__ __launch_bounds__(256)
void k_prep1(const float* __restrict__ om, const float* __restrict__ prot,
             ushort_t* __restrict__ omh_r, ushort_t* __restrict__ oml_r,
             ushort_t* __restrict__ omTh, ushort_t* __restrict__ omTl,
             ushort_t* __restrict__ omh_sw,
             ushort_t* __restrict__ phl, ushort_t* __restrict__ pll) {
    const int bid = blockIdx.x, tid = threadIdx.x;
    if (bid < 256) {
        const int tr = bid >> 4, tc = bid & 15;
        __shared__ float tile[64][65];
        const int r0 = tid >> 4, cq = (tid & 15) * 4;
#pragma unroll
        for (int i = 0; i < 4; ++i) {
            const int row = r0 + i * 16;
            const int gr = tr * 64 + row;
            float4 v = *reinterpret_cast<const float4*>(om + (size_t)gr * F_ + tc * 64 + cq);
            tile[row][cq + 0] = v.x; tile[row][cq + 1] = v.y;
            tile[row][cq + 2] = v.z; tile[row][cq + 3] = v.w;
            unsigned h0 = pk2(v.x, v.y), h1 = pk2(v.z, v.w);
            unsigned l0 = pk2(v.x - lo_f(h0), v.y - hi_f(h0));
            unsigned l1 = pk2(v.z - lo_f(h1), v.w - hi_f(h1));
            size_t ro = (size_t)gr * F_ + tc * 64 + cq;
            *reinterpret_cast<uint2*>(omh_r + ro) = make_uint2(h0, h1);
            *reinterpret_cast<uint2*>(oml_r + ro) = make_uint2(l0, l1);
            // pre-swizzled hi layout: [rb][t32][128x32 tile, 16B-chunk XOR swizzle]
            const int rb = gr >> 7, r = gr & 127;
            const int c0 = tc * 64 + cq;
            const int t32 = c0 >> 5, k8 = (c0 >> 3) & 3, half = (c0 >> 2) & 1;
            size_t base = ((size_t)(rb * 32 + t32)) * 8192;
            int off = (r * 64 + k8 * 16) ^ ((r & 7) << 4);
            *reinterpret_cast<uint2*>(reinterpret_cast<char*>(omh_sw) + base + off + half * 8) =
                make_uint2(h0, h1);
        }
        __syncthreads();
#pragma unroll
        for (int i = 0; i < 4; ++i) {
            const int rowT = r0 + i * 16;                 // omT row-in-tile (om col)
            float a = tile[cq + 0][rowT], b = tile[cq + 1][rowT];
            float c = tile[cq + 2][rowT], d = tile[cq + 3][rowT];
            unsigned h0 = pk2(a, b), h1 = pk2(c, d);
            unsigned l0 = pk2(a - lo_f(h0), b - hi_f(h0));
            unsigned l1 = pk2(c - lo_f(h1), d - hi_f(h1));
            size_t to = (size_t)(tc * 64 + rowT) * F_ + tr * 64 + cq;
            *reinterpret_cast<uint2*>(omTh + to) = make_uint2(h0, h1);
            *reinterpret_cast<uint2*>(omTl + to) = make_uint2(l0, l1);
        }
    } else {
        const int pb = bid - 256;
        const int row = pb * 16 + (tid >> 4);
#pragma unroll
        for (int i = 0; i < 16; ++i) {
            const int col = (tid & 15) * 4 + i * 64;
            float4 v = *reinterpret_cast<const float4*>(prot + (size_t)row * F_ + col);
            unsigned h0 = pk2(v.x, v.y), h1 = pk2(v.z, v.w);
            unsigned l0 = pk2(v.x - lo_f(h0), v.y - hi_f(h0));
            unsigned l1 = pk2(v.z - lo_f(h1), v.w - hi_f(h1));
            size_t ro = (size_t)row * F_ + col;
            *reinterpret_cast<uint2*>(phl + ro) = make_uint2(h0, h1);
            *reinterpret_cast<uint2*>(pll + ro) = make_uint2(l0, l1);
        }
    }
}

// ---- k_zp2: zp = prot @ om^T (split operands), fused sqp, split output ---
// 160 blocks x 4 waves; wave fid = bid*4+w owns frag (m = fid>>6, n = fid&63),
// full K = 1024. Barrier-free, LDS-free.
__global__ __launch_bounds__(256)
void k_zp2(const ushort_t* __restrict__ phl, const ushort_t* __restrict__ pll,
           const ushort_t* __restrict__ omh_r, const ushort_t* __restrict__ oml_r,
           ushort_t* __restrict__ zph, ushort_t* __restrict__ zpl,
           float* __restrict__ sqp) {
    const int tid = threadIdx.x, lane = tid & 63, w = tid >> 6;
    const int fid = blockIdx.x * 4 + w;
    const int m = fid >> 6, n = fid & 63;
    const int l15 = lane & 15, g = lane >> 4;

    f32x4 acc = {};
    const ushort_t* pa_h = phl + (size_t)(m * 16 + l15) * F_ + g * 8;
    const ushort_t* pa_l = pll + (size_t)(m * 16 + l15) * F_ + g * 8;
    const ushort_t* pb_h = omh_r + (size_t)(n * 16 + l15) * F_ + g * 8;
    const ushort_t* pb_l = oml_r + (size_t)(n * 16 + l15) * F_ + g * 8;
#pragma unroll 4
    for (int ks = 0; ks < 32; ++ks) {
        short8 ah = *reinterpret_cast<const short8*>(pa_h + ks * 32);
        short8 al = *reinterpret_cast<const short8*>(pa_l + ks * 32);
        short8 bh = *reinterpret_cast<const short8*>(pb_h + ks * 32);
        short8 bl = *reinterpret_cast<const short8*>(pb_l + ks * 32);
        acc = __builtin_amdgcn_mfma_f32_16x16x32_bf16(ah, bh, acc, 0, 0, 0);
        acc = __builtin_amdgcn_mfma_f32_16x16x32_bf16(al, bh, acc, 0, 0, 0);
        acc = __builtin_amdgcn_mfma_f32_16x16x32_bf16(ah, bl, acc, 0, 0, 0);
    }
#pragma unroll
    for (int j = 0; j < 4; ++j) {
        float v = acc[j];
        const int row = m * 16 + g * 4 + j, col = n * 16 + l15;
        unsigned hv = pk2(v, 0.f);
        float hf = lo_f(hv);
        unsigned lv = pk2(v - hf, 0.f);
        zph[(size_t)row * F_ + col] = (ushort_t)hv;
        zpl[(size_t)row * F_ + col] = (ushort_t)lv;
        float s = v * v;
        s += __shfl_xor(s, 1); s += __shfl_xor(s, 2);
        s += __shfl_xor(s, 4); s += __shfl_xor(s, 8);
        if (l15 == 0) atomicAdd(&sqp[row], s);
    }
}

// ---- k_u2: u = zp @ om (via omT splits), split output --------------------
__global__ __launch_bounds__(256)
void k_u2(const ushort_t* __restrict__ zph, const ushort_t* __restrict__ zpl,
          const ushort_t* __restrict__ omTh, const ushort_t* __restrict__ omTl,
          ushort_t* __restrict__ uh, ushort_t* __restrict__ ul) {
    const int tid = threadIdx.x, lane = tid & 63, w = tid >> 6;
    const int fid = blockIdx.x * 4 + w;
    const int m = fid >> 6, n = fid & 63;
    const int l15 = lane & 15, g = lane >> 4;

    f32x4 acc = {};
    const ushort_t* pa_h = zph + (size_t)(m * 16 + l15) * F_ + g * 8;
    const ushort_t* pa_l = zpl + (size_t)(m * 16 + l15) * F_ + g * 8;
    const ushort_t* pb_h = omTh + (size_t)(n * 16 + l15) * F_ + g * 8;
    const ushort_t* pb_l = omTl + (size_t)(n * 16 + l15) * F_ + g * 8;
#pragma unroll 4
    for (int ks = 0; ks < 32; ++ks) {
        short8 ah = *reinterpret_cast<const short8*>(pa_h + ks * 32);
        short8 al = *reinterpret_cast<const short8*>(pa_l + ks * 32);
        short8 bh = *reinterpret_cast<const short8*>(pb_h + ks * 32);
        short8 bl = *reinterpret_cast<const short8*>(pb_l + ks * 32);
        acc = __builtin_amdgcn_mfma_f32_16x16x32_bf16(ah, bh, acc, 0, 0, 0);
        acc = __builtin_amdgcn_mfma_f32_16x16x32_bf16(al, bh, acc, 0, 0, 0);
        acc = __builtin_amdgcn_mfma_f32_16x16x32_bf16(ah, bl, acc, 0, 0, 0);
    }
#pragma unroll
    for (int j = 0; j < 4; ++j) {
        float v = acc[j];
        const int row = m * 16 + g * 4 + j, col = n * 16 + l15;
        unsigned hv = pk2(v, 0.f);
        float hf = lo_f(hv);
        unsigned lv = pk2(v - hf, 0.f);
        uh[(size_t)row * F_ + col] = (ushort_t)hv;
        ul[(size_t)row * F_ + col] = (ushort_t)lv;
    }
}

// ---- k_cvt_sw: x -> pre-swizzled bf16 tiled layout -----------------------
__global__ __launch_bounds__(256)
void k_cvt_sw(const float* __restrict__ src, ushort_t* __restrict__ dst) {
    const int c = blockIdx.x * 256 + threadIdx.x;
    const int rg = c >> 7, kg = c & 127;
    const int t = kg >> 2, k8 = kg & 3;
    const float4* s4 = reinterpret_cast<const float4*>(src + (size_t)rg * F_ + t * 32 + k8 * 8);
    float4 v0 = s4[0], v1 = s4[1];
    uint4 o;
    o.x = pk2(v0.x, v0.y); o.y = pk2(v0.z, v0.w);
    o.z = pk2(v1.x, v1.y); o.w = pk2(v1.z, v1.w);
    const int rb = rg >> 7, r = rg & 127;
    size_t base = ((size_t)(rb * 32 + t)) * 8192;
    int off = (r * 64 + k8 * 16) ^ ((r & 7) << 4);
    *reinterpret_cast<uint4*>(reinterpret_cast<char*>(dst) + base + off) = o;
}

// ---- k_z_sqx2: sq_x via bf16 MFMA GEMM with global_load_lds --------------
__global__ __launch_bounds__(256)
void k_z_sqx2(const ushort_t* __restrict__ xh, const ushort_t* __restrict__ omh,
              float* __restrict__ sqx) {
    const int bx = blockIdx.x, by = blockIdx.y;
    __shared__ __align__(16) ushort_t sA[128 * 32];
    __shared__ __align__(16) ushort_t sB[128 * 32];
    const int tid = threadIdx.x;
    const int lane = tid & 63, w = tid >> 6;
    const int wr = (w >> 1) * 64, wc = (w & 1) * 64;
    const int l15 = lane & 15, g = lane >> 4;

    f32x4 acc[4][4] = {};
    const char* xb = reinterpret_cast<const char*>(xh) + (size_t)bx * 32 * 8192;
    const char* ob = reinterpret_cast<const char*>(omh) + (size_t)by * 32 * 8192;
    char* sAc = reinterpret_cast<char*>(sA);
    char* sBc = reinterpret_cast<char*>(sB);

    for (int t = 0; t < 32; ++t) {
        __syncthreads();
        gload16(xb + (size_t)t * 8192 + tid * 16,        sAc + tid * 16);
        gload16(xb + (size_t)t * 8192 + 4096 + tid * 16, sAc + 4096 + tid * 16);
        gload16(ob + (size_t)t * 8192 + tid * 16,        sBc + tid * 16);
        gload16(ob + (size_t)t * 8192 + 4096 + tid * 16, sBc + 4096 + tid * 16);
        __syncthreads();
        short8 a[4], b[4];
#pragma unroll
        for (int m = 0; m < 4; ++m) {
            int row = wr + m * 16 + l15;
            int off = (row * 64 + g * 16) ^ ((row & 7) << 4);
            a[m] = *reinterpret_cast<const short8*>(sAc + off);
        }
#pragma unroll
        for (int n = 0; n < 4; ++n) {
            int row = wc + n * 16 + l15;
            int off = (row * 64 + g * 16) ^ ((row & 7) << 4);
            b[n] = *reinterpret_cast<const short8*>(sBc + off);
        }
#pragma unroll
        for (int m = 0; m < 4; ++m)
#pragma unroll
            for (int n = 0; n < 4; ++n)
                acc[m][n] = __builtin_amdgcn_mfma_f32_16x16x32_bf16(a[m], b[n], acc[m][n], 0, 0, 0);
    }
#pragma unroll
    for (int m = 0; m < 4; ++m) {
#pragma unroll
        for (int j = 0; j < 4; ++j) {
            float s = 0.f;
#pragma unroll
            for (int n = 0; n < 4; ++n) { float v = acc[m][n][j]; s = fmaf(v, v, s); }
            s += __shfl_xor(s, 1); s += __shfl_xor(s, 2);
            s += __shfl_xor(s, 4); s += __shfl_xor(s, 8);
            if (l15 == 0) atomicAdd(&sqx[bx * 128 + wr + m * 16 + g * 4 + j], s);
        }
    }
}

// ---- k_z_sqx: fallback with inline convert -------------------------------
__global__ __launch_bounds__(256)
void k_z_sqx(const float* __restrict__ x, const float* __restrict__ om,
             float* __restrict__ sqx) {
    const int brow = blockIdx.x * 128;
    const int bcol = blockIdx.y * 128;
    __shared__ __align__(16) ushort_t sA[128 * 32];
    __shared__ __align__(16) ushort_t sB[128 * 32];
    const int tid = threadIdx.x;
    const int lane = tid & 63, w = tid >> 6;
    const int wr = (w >> 1) * 64, wc = (w & 1) * 64;
    const int l15 = lane & 15, g = lane >> 4;
    f32x4 acc[4][4] = {};
    for (int k0 = 0; k0 < F_; k0 += 32) {
        __syncthreads();
#pragma unroll
        for (int j = 0; j < 4; ++j) {
            int idx = tid + j * 256;
            int row = idx >> 3, c4 = idx & 7;
            float4 va = *reinterpret_cast<const float4*>(x  + (size_t)(brow + row) * F_ + k0 + c4 * 4);
            float4 vb = *reinterpret_cast<const float4*>(om + (size_t)(bcol + row) * F_ + k0 + c4 * 4);
            int off = (row * 64 + c4 * 8) ^ ((row & 7) << 4);
            *reinterpret_cast<uint2*>(reinterpret_cast<char*>(sA) + off) =
                make_uint2(pk2(va.x, va.y), pk2(va.z, va.w));
            *reinterpret_cast<uint2*>(reinterpret_cast<char*>(sB) + off) =
                make_uint2(pk2(vb.x, vb.y), pk2(vb.z, vb.w));
        }
        __syncthreads();
        short8 a[4], b[4];
#pragma unroll
        for (int m = 0; m < 4; ++m) {
            int row = wr + m * 16 + l15;
            int off = (row * 64 + g * 16) ^ ((row & 7) << 4);
            a[m] = *reinterpret_cast<const short8*>(reinterpret_cast<const char*>(sA) + off);
        }
#pragma unroll
        for (int n = 0; n < 4; ++n) {
            int row = wc + n * 16 + l15;
            int off = (row * 64 + g * 16) ^ ((row & 7) << 4);
            b[n] = *reinterpret_cast<const short8*>(reinterpret_cast<const char*>(sB) + off);
        }
#pragma unroll
        for (int m = 0; m < 4; ++m)
#pragma unroll
            for (int n = 0; n < 4; ++n)
                acc[m][n] = __builtin_amdgcn_mfma_f32_16x16x32_bf16(a[m], b[n], acc[m][n], 0, 0, 0);
    }
#pragma unroll
    for (int m = 0; m < 4; ++m) {
#pragma unroll
        for (int j = 0; j < 4; ++j) {
            float s = 0.f;
#pragma unroll
            for (int n = 0; n < 4; ++n) { float v = acc[m][n][j]; s = fmaf(v, v, s); }
            s += __shfl_xor(s, 1); s += __shfl_xor(s, 2);
            s += __shfl_xor(s, 4); s += __shfl_xor(s, 8);
            if (l15 == 0) atomicAdd(&sqx[brow + wr + m * 16 + g * 4 + j], s);
        }
    }
}

// ---- K2: distances + predictions, barrier-free K-split -------------------
__global__ __launch_bounds__(256)
void k_dist2(const float* __restrict__ x, const ushort_t* __restrict__ uh,
             const ushort_t* __restrict__ ul, const float* __restrict__ sqx,
             const float* __restrict__ sqp, float* __restrict__ dist,
             float* __restrict__ pred) {
    const int brow = blockIdx.x * 16;
    const int tid = threadIdx.x, lane = tid & 63, w = tid >> 6;
    const int l15 = lane & 15, g = lane >> 4;
    __shared__ float red[4][10][16][16];

    f32x4 acc[10] = {};
    const float* xp = x + (size_t)(brow + l15) * F_ + w * 256 + g * 8;
    const ushort_t* buh = uh + (size_t)l15 * F_ + w * 256 + g * 8;
    const ushort_t* bul = ul + (size_t)l15 * F_ + w * 256 + g * 8;

#pragma unroll 2
    for (int ks = 0; ks < 8; ++ks) {
        float4 v0 = *reinterpret_cast<const float4*>(xp + ks * 32);
        float4 v1 = *reinterpret_cast<const float4*>(xp + ks * 32 + 4);
        union { unsigned u[4]; short8 s; } cva, cvl;
        cva.u[0] = pk2(v0.x, v0.y); cva.u[1] = pk2(v0.z, v0.w);
        cva.u[2] = pk2(v1.x, v1.y); cva.u[3] = pk2(v1.z, v1.w);
        cvl.u[0] = pk2(v0.x - lo_f(cva.u[0]), v0.y - hi_f(cva.u[0]));
        cvl.u[1] = pk2(v0.z - lo_f(cva.u[1]), v0.w - hi_f(cva.u[1]));
        cvl.u[2] = pk2(v1.x - lo_f(cva.u[2]), v1.y - hi_f(cva.u[2]));
        cvl.u[3] = pk2(v1.z - lo_f(cva.u[3]), v1.w - hi_f(cva.u[3]));
        short8 ah = cva.s, al = cvl.s;
#pragma unroll
        for (int f = 0; f < 10; ++f) {
            short8 bh = *reinterpret_cast<const short8*>(buh + (size_t)f * 16 * F_ + ks * 32);
            short8 bl = *reinterpret_cast<const short8*>(bul + (size_t)f * 16 * F_ + ks * 32);
            acc[f] = __builtin_amdgcn_mfma_f32_16x16x32_bf16(ah, bh, acc[f], 0, 0, 0);
            acc[f] = __builtin_amdgcn_mfma_f32_16x16x32_bf16(al, bh, acc[f], 0, 0, 0);
            acc[f] = __builtin_amdgcn_mfma_f32_16x16x32_bf16(ah, bl, acc[f], 0, 0, 0);
        }
    }

#pragma unroll
    for (int f = 0; f < 10; ++f)
#pragma unroll
        for (int j = 0; j < 4; ++j) red[w][f][g * 4 + j][l15] = acc[f][j];
    __syncthreads();

    const int m = tid >> 4, n = tid & 15;
    const int row = brow + m;
    float sx = sqx[row];
    float best = 3.4e38f; int bi = 0;
#pragma unroll
    for (int f = 0; f < 10; ++f) {
        float d = red[0][f][m][n] + red[1][f][m][n] + red[2][f][m][n] + red[3][f][m][n];
        float dv = sx + sqp[f * 16 + n] - 2.f * d;
        dist[(size_t)row * P_ + f * 16 + n] = dv;
        float mn = dv;
        mn = fminf(mn, __shfl_xor(mn, 1));
        mn = fminf(mn, __shfl_xor(mn, 2));
        mn = fminf(mn, __shfl_xor(mn, 4));
        mn = fminf(mn, __shfl_xor(mn, 8));
        if (mn < best) { best = mn; bi = f; }
    }
    if (n == 0) pred[row] = (float)bi;
}

// ---- old-path kernels (tier-3 fallback, R3 verbatim) ---------------------

__global__ __launch_bounds__(256)
void k_proj(const float* __restrict__ prot, const float* __restrict__ om,
            float* __restrict__ zp, float* __restrict__ sqp) {
    const int n0 = blockIdx.x * 16;
    const int tid = threadIdx.x, lane = tid & 63, w = tid >> 6;
    const int l15 = lane & 15, g = lane >> 4;
    __shared__ float red[4][10][16][16];
    f32x4 acc[10] = {};
    const float* op = om   + (size_t)(n0 + l15) * F_ + w * 256 + g * 8;
    const float* pp = prot + (size_t)l15 * F_ + w * 256 + g * 8;
#pragma unroll 2
    for (int ks = 0; ks < 8; ++ks) {
        float4 b0 = *reinterpret_cast<const float4*>(op + ks * 32);
        float4 b1 = *reinterpret_cast<const float4*>(op + ks * 32 + 4);
        union { unsigned u[4]; short8 s; } cbh, cbl;
        cbh.u[0] = pk2(b0.x, b0.y); cbh.u[1] = pk2(b0.z, b0.w);
        cbh.u[2] = pk2(b1.x, b1.y); cbh.u[3] = pk2(b1.z, b1.w);
        cbl.u[0] = pk2(b0.x - lo_f(cbh.u[0]), b0.y - hi_f(cbh.u[0]));
        cbl.u[1] = pk2(b0.z - lo_f(cbh.u[1]), b0.w - hi_f(cbh.u[1]));
        cbl.u[2] = pk2(b1.x - lo_f(cbh.u[2]), b1.y - hi_f(cbh.u[2]));
        cbl.u[3] = pk2(b1.z - lo_f(cbh.u[3]), b1.w - hi_f(cbh.u[3]));
        short8 bh = cbh.s, bl = cbl.s;
#pragma unroll
        for (int f = 0; f < 10; ++f) {
            float4 a0 = *reinterpret_cast<const float4*>(pp + (size_t)f * 16 * F_ + ks * 32);
            float4 a1 = *reinterpret_cast<const float4*>(pp + (size_t)f * 16 * F_ + ks * 32 + 4);
            union { unsigned u[4]; short8 s; } cah, cal;
            cah.u[0] = pk2(a0.x, a0.y); cah.u[1] = pk2(a0.z, a0.w);
            cah.u[2] = pk2(a1.x, a1.y); cah.u[3] = pk2(a1.z, a1.w);
            cal.u[0] = pk2(a0.x - lo_f(cah.u[0]), a0.y - hi_f(cah.u[0]));
            cal.u[1] = pk2(a0.z - lo_f(cah.u[1]), a0.w - hi_f(cah.u[1]));
            cal.u[2] = pk2(a1.x - lo_f(cah.u[2]), a1.y - hi_f(cah.u[2]));
            cal.u[3] = pk2(a1.z - lo_f(cah.u[3]), a1.w - hi_f(cah.u[3]));
            acc[f] = __builtin_amdgcn_mfma_f32_16x16x32_bf16(cah.s, bh, acc[f], 0, 0, 0);
            acc[f] = __builtin_amdgcn_mfma_f32_16x16x32_bf16(cal.s, bh, acc[f], 0, 0, 0);
            acc[f] = __builtin_amdgcn_mfma_f32_16x16x32_bf16(cah.s, bl, acc[f], 0, 0, 0);
        }
    }
#pragma unroll
    for (int f = 0; f < 10; ++f)
#pragma unroll
        for (int j = 0; j < 4; ++j) red[w][f][g * 4 + j][l15] = acc[f][j];
    __syncthreads();
    if (tid < 160) {
        const int f = tid >> 4, m = tid & 15;
        float s = 0.f;
#pragma unroll
        for (int n = 0; n < 16; ++n) {
            float v = red[0][f][m][n] + red[1][f][m][n] + red[2][f][m][n] + red[3][f][m][n];
            zp[(size_t)tid * F_ + n0 + n] = v;
            s = fmaf(v, v, s);
        }
        atomicAdd(&sqp[tid], s);
    }
}

__global__ __launch_bounds__(128)
void k_u(const float* __restrict__ zp, const float* __restrict__ om,
         float* __restrict__ u) {
    const int c  = blockIdx.x * 128 + threadIdx.x;
    const int r0 = blockIdx.y * 32;
    const int kz = blockIdx.z * 128;
    __shared__ __align__(16) float zt[128][36];
    for (int i = threadIdx.x; i < 128 * 32; i += 128) {
        int k = i >> 5, r = i & 31;
        zt[k][r] = zp[(size_t)(r0 + r) * F_ + kz + k];
    }
    __syncthreads();
    float acc[32];
#pragma unroll
    for (int r = 0; r < 32; ++r) acc[r] = 0.f;
    for (int k = 0; k < 128; ++k) {
        float o = om[(size_t)(kz + k) * F_ + c];
        const float4* zr = reinterpret_cast<const float4*>(&zt[k][0]);
#pragma unroll
        for (int r4 = 0; r4 < 8; ++r4) {
            float4 z4 = zr[r4];
            acc[r4 * 4 + 0] = fmaf(z4.x, o, acc[r4 * 4 + 0]);
            acc[r4 * 4 + 1] = fmaf(z4.y, o, acc[r4 * 4 + 1]);
            acc[r4 * 4 + 2] = fmaf(z4.z, o, acc[r4 * 4 + 2]);
            acc[r4 * 4 + 3] = fmaf(z4.w, o, acc[r4 * 4 + 3]);
        }
    }
#pragma unroll
    for (int r = 0; r < 32; ++r) atomicAdd(&u[(size_t)(r0 + r) * F_ + c], acc[r]);
}

__global__ __launch_bounds__(256)
void k_usplit(const float* __restrict__ u, ushort_t* __restrict__ uh,
              ushort_t* __restrict__ ul) {
    const int b = blockIdx.x, t = threadIdx.x;
    float4 v = *reinterpret_cast<const float4*>(u + (size_t)b * F_ + t * 4);
    unsigned h0 = pk2(v.x, v.y), h1 = pk2(v.z, v.w);
    unsigned q0 = pk2(v.x - lo_f(h0), v.y - hi_f(h0));
    unsigned q1 = pk2(v.z - lo_f(h1), v.w - hi_f(h1));
    *reinterpret_cast<uint2*>(uh + (size_t)b * F_ + t * 4) = make_uint2(h0, h1);
    *reinterpret_cast<uint2*>(ul + (size_t)b * F_ + t * 4) = make_uint2(q0, q1);
}

// ---- launch --------------------------------------------------------------

extern "C" void kernel_launch(void* const* d_in, const int* in_sizes, int n_in,
                              void* d_out, int out_size, void* d_ws, size_t ws_size,
                              hipStream_t stream) {
    (void)in_sizes; (void)n_in; (void)out_size;
    const float* x    = (const float*)d_in[0];
    const float* prot = (const float*)d_in[1];
    const float* om   = (const float*)d_in[2];

    float* out  = (float*)d_out;
    float* dist = out;
    float* pred = out + (size_t)B_ * P_;

    char* W = (char*)d_ws;
    float* sqx = (float*)W;                    // 32768 B
    float* sqp = (float*)(W + 32768);          // 1024 B
    size_t o = 33792;
    ushort_t* phl   = (ushort_t*)(W + o); o += 327680;
    ushort_t* pll   = (ushort_t*)(W + o); o += 327680;
    ushort_t* zph   = (ushort_t*)(W + o); o += 327680;
    ushort_t* zpl   = (ushort_t*)(W + o); o += 327680;
    ushort_t* uh    = (ushort_t*)(W + o); o += 327680;
    ushort_t* ul    = (ushort_t*)(W + o); o += 327680;
    ushort_t* omh_r = (ushort_t*)(W + o); o += 2097152;
    ushort_t* oml_r = (ushort_t*)(W + o); o += 2097152;
    ushort_t* omTh  = (ushort_t*)(W + o); o += 2097152;
    ushort_t* omTl  = (ushort_t*)(W + o); o += 2097152;
    ushort_t* omh_sw= (ushort_t*)(W + o); o += 2097152;   // ~12.49 MB so far
    ushort_t* xh    = (ushort_t*)(W + o);                 // +16 MB -> ~29.3 MB

    const int tier = (ws_size >= (size_t)30 * 1024 * 1024) ? 2
                   : (ws_size >= (size_t)13 * 1024 * 1024) ? 1 : 0;

    hipMemsetAsync(sqx, 0, 8192 * sizeof(float), stream);
    hipMemsetAsync(sqp, 0, 256 * sizeof(float), stream);

    if (tier >= 1) {
        k_prep1<<<266, 256, 0, stream>>>(om, prot, omh_r, oml_r, omTh, omTl,
                                         omh_sw, phl, pll);
        k_zp2  <<<160, 256, 0, stream>>>(phl, pll, omh_r, oml_r, zph, zpl, sqp);
        k_u2   <<<160, 256, 0, stream>>>(zph, zpl, omTh, omTl, uh, ul);
        if (tier == 2) {
            k_cvt_sw<<<4096, 256, 0, stream>>>(x, xh);
            k_z_sqx2<<<dim3(64, 8), 256, 0, stream>>>(xh, omh_sw, sqx);
        } else {
            k_z_sqx <<<dim3(64, 8), 256, 0, stream>>>(x, om, sqx);
        }
        k_dist2<<<512, 256, 0, stream>>>(x, uh, ul, sqx, sqp, dist, pred);
    } else {
        // tier-0: R3 path (ws >= ~1.35 MB known-good)
        float* wsf = (float*)d_ws;
        float* zp  = wsf + 8448;
        float* u   = wsf + 172288;
        ushort_t* uh0 = (ushort_t*)(wsf + 8448);
        ushort_t* ul0 = uh0 + 163840;
        hipMemsetAsync(u, 0, (size_t)P_ * F_ * sizeof(float), stream);
        k_proj  <<<64, 256, 0, stream>>>(prot, om, zp, sqp);
        k_u     <<<dim3(8, 5, 8), 128, 0, stream>>>(zp, om, u);
        k_usplit<<<160, 256, 0, stream>>>(u, uh0, ul0);
        k_z_sqx <<<dim3(64, 8), 256, 0, stream>>>(x, om, sqx);
        k_dist2 <<<512, 256, 0, stream>>>(x, uh0, ul0, sqx, sqp, dist, pred);
    }
}

// Round 5
// 116.004 us; speedup vs baseline: 2.0577x; 1.1559x over previous
//
#include <hip/hip_runtime.h>
#include <hip/hip_bf16.h>

#define B_ 8192
#define F_ 1024
#define P_ 160
#define C_ 10

typedef __attribute__((ext_vector_type(8))) short short8;
typedef __attribute__((ext_vector_type(4))) float f32x4;
typedef unsigned short ushort_t;

// ---- helpers -------------------------------------------------------------

__device__ inline unsigned pk2(float a, float b) {
    __hip_bfloat162 h = __float22bfloat162_rn(make_float2(a, b));
    return *reinterpret_cast<unsigned*>(&h);
}
__device__ inline float lo_f(unsigned u) { return __uint_as_float(u << 16); }
__device__ inline float hi_f(unsigned u) { return __uint_as_float(u & 0xffff0000u); }

__device__ inline void gload16(const void* g, void* l) {
    __builtin_amdgcn_global_load_lds((const __attribute__((address_space(1))) unsigned*)g,
                                     (__attribute__((address_space(3))) unsigned*)l, 16, 0, 0);
}

// ---- k_prep1: all operand conversions in one pass ------------------------
__global__ __launch_bounds__(256)
void k_prep1(const float* __restrict__ om, const float* __restrict__ prot,
             ushort_t* __restrict__ omh_r, ushort_t* __restrict__ oml_r,
             ushort_t* __restrict__ omTh, ushort_t* __restrict__ omTl,
             ushort_t* __restrict__ omh_sw,
             ushort_t* __restrict__ phl, ushort_t* __restrict__ pll) {
    const int bid = blockIdx.x, tid = threadIdx.x;
    if (bid < 256) {
        const int tr = bid >> 4, tc = bid & 15;
        __shared__ float tile[64][65];
        const int r0 = tid >> 4, cq = (tid & 15) * 4;
#pragma unroll
        for (int i = 0; i < 4; ++i) {
            const int row = r0 + i * 16;
            const int gr = tr * 64 + row;
            float4 v = *reinterpret_cast<const float4*>(om + (size_t)gr * F_ + tc * 64 + cq);
            tile[row][cq + 0] = v.x; tile[row][cq + 1] = v.y;
            tile[row][cq + 2] = v.z; tile[row][cq + 3] = v.w;
            unsigned h0 = pk2(v.x, v.y), h1 = pk2(v.z, v.w);
            unsigned l0 = pk2(v.x - lo_f(h0), v.y - hi_f(h0));
            unsigned l1 = pk2(v.z - lo_f(h1), v.w - hi_f(h1));
            size_t ro = (size_t)gr * F_ + tc * 64 + cq;
            *reinterpret_cast<uint2*>(omh_r + ro) = make_uint2(h0, h1);
            *reinterpret_cast<uint2*>(oml_r + ro) = make_uint2(l0, l1);
            const int rb = gr >> 7, r = gr & 127;
            const int c0 = tc * 64 + cq;
            const int t32 = c0 >> 5, k8 = (c0 >> 3) & 3, half = (c0 >> 2) & 1;
            size_t base = ((size_t)(rb * 32 + t32)) * 8192;
            int off = (r * 64 + k8 * 16) ^ ((r & 7) << 4);
            *reinterpret_cast<uint2*>(reinterpret_cast<char*>(omh_sw) + base + off + half * 8) =
                make_uint2(h0, h1);
        }
        __syncthreads();
#pragma unroll
        for (int i = 0; i < 4; ++i) {
            const int rowT = r0 + i * 16;
            float a = tile[cq + 0][rowT], b = tile[cq + 1][rowT];
            float c = tile[cq + 2][rowT], d = tile[cq + 3][rowT];
            unsigned h0 = pk2(a, b), h1 = pk2(c, d);
            unsigned l0 = pk2(a - lo_f(h0), b - hi_f(h0));
            unsigned l1 = pk2(c - lo_f(h1), d - hi_f(h1));
            size_t to = (size_t)(tc * 64 + rowT) * F_ + tr * 64 + cq;
            *reinterpret_cast<uint2*>(omTh + to) = make_uint2(h0, h1);
            *reinterpret_cast<uint2*>(omTl + to) = make_uint2(l0, l1);
        }
    } else {
        const int pb = bid - 256;
        const int row = pb * 16 + (tid >> 4);
#pragma unroll
        for (int i = 0; i < 16; ++i) {
            const int col = (tid & 15) * 4 + i * 64;
            float4 v = *reinterpret_cast<const float4*>(prot + (size_t)row * F_ + col);
            unsigned h0 = pk2(v.x, v.y), h1 = pk2(v.z, v.w);
            unsigned l0 = pk2(v.x - lo_f(h0), v.y - hi_f(h0));
            unsigned l1 = pk2(v.z - lo_f(h1), v.w - hi_f(h1));
            size_t ro = (size_t)row * F_ + col;
            *reinterpret_cast<uint2*>(phl + ro) = make_uint2(h0, h1);
            *reinterpret_cast<uint2*>(pll + ro) = make_uint2(l0, l1);
        }
    }
}

// ---- k_zp2: zp = prot @ om^T (split operands), fused sqp -----------------
__global__ __launch_bounds__(256)
void k_zp2(const ushort_t* __restrict__ phl, const ushort_t* __restrict__ pll,
           const ushort_t* __restrict__ omh_r, const ushort_t* __restrict__ oml_r,
           ushort_t* __restrict__ zph, ushort_t* __restrict__ zpl,
           float* __restrict__ sqp) {
    const int tid = threadIdx.x, lane = tid & 63, w = tid >> 6;
    const int fid = blockIdx.x * 4 + w;
    const int m = fid >> 6, n = fid & 63;
    const int l15 = lane & 15, g = lane >> 4;

    f32x4 acc = {};
    const ushort_t* pa_h = phl + (size_t)(m * 16 + l15) * F_ + g * 8;
    const ushort_t* pa_l = pll + (size_t)(m * 16 + l15) * F_ + g * 8;
    const ushort_t* pb_h = omh_r + (size_t)(n * 16 + l15) * F_ + g * 8;
    const ushort_t* pb_l = oml_r + (size_t)(n * 16 + l15) * F_ + g * 8;
#pragma unroll 4
    for (int ks = 0; ks < 32; ++ks) {
        short8 ah = *reinterpret_cast<const short8*>(pa_h + ks * 32);
        short8 al = *reinterpret_cast<const short8*>(pa_l + ks * 32);
        short8 bh = *reinterpret_cast<const short8*>(pb_h + ks * 32);
        short8 bl = *reinterpret_cast<const short8*>(pb_l + ks * 32);
        acc = __builtin_amdgcn_mfma_f32_16x16x32_bf16(ah, bh, acc, 0, 0, 0);
        acc = __builtin_amdgcn_mfma_f32_16x16x32_bf16(al, bh, acc, 0, 0, 0);
        acc = __builtin_amdgcn_mfma_f32_16x16x32_bf16(ah, bl, acc, 0, 0, 0);
    }
#pragma unroll
    for (int j = 0; j < 4; ++j) {
        float v = acc[j];
        const int row = m * 16 + g * 4 + j, col = n * 16 + l15;
        unsigned hv = pk2(v, 0.f);
        float hf = lo_f(hv);
        unsigned lv = pk2(v - hf, 0.f);
        zph[(size_t)row * F_ + col] = (ushort_t)hv;
        zpl[(size_t)row * F_ + col] = (ushort_t)lv;
        float s = v * v;
        s += __shfl_xor(s, 1); s += __shfl_xor(s, 2);
        s += __shfl_xor(s, 4); s += __shfl_xor(s, 8);
        if (l15 == 0) atomicAdd(&sqp[row], s);
    }
}

// ---- k_u2: u = zp @ om (via omT splits) ----------------------------------
__global__ __launch_bounds__(256)
void k_u2(const ushort_t* __restrict__ zph, const ushort_t* __restrict__ zpl,
          const ushort_t* __restrict__ omTh, const ushort_t* __restrict__ omTl,
          ushort_t* __restrict__ uh, ushort_t* __restrict__ ul) {
    const int tid = threadIdx.x, lane = tid & 63, w = tid >> 6;
    const int fid = blockIdx.x * 4 + w;
    const int m = fid >> 6, n = fid & 63;
    const int l15 = lane & 15, g = lane >> 4;

    f32x4 acc = {};
    const ushort_t* pa_h = zph + (size_t)(m * 16 + l15) * F_ + g * 8;
    const ushort_t* pa_l = zpl + (size_t)(m * 16 + l15) * F_ + g * 8;
    const ushort_t* pb_h = omTh + (size_t)(n * 16 + l15) * F_ + g * 8;
    const ushort_t* pb_l = omTl + (size_t)(n * 16 + l15) * F_ + g * 8;
#pragma unroll 4
    for (int ks = 0; ks < 32; ++ks) {
        short8 ah = *reinterpret_cast<const short8*>(pa_h + ks * 32);
        short8 al = *reinterpret_cast<const short8*>(pa_l + ks * 32);
        short8 bh = *reinterpret_cast<const short8*>(pb_h + ks * 32);
        short8 bl = *reinterpret_cast<const short8*>(pb_l + ks * 32);
        acc = __builtin_amdgcn_mfma_f32_16x16x32_bf16(ah, bh, acc, 0, 0, 0);
        acc = __builtin_amdgcn_mfma_f32_16x16x32_bf16(al, bh, acc, 0, 0, 0);
        acc = __builtin_amdgcn_mfma_f32_16x16x32_bf16(ah, bl, acc, 0, 0, 0);
    }
#pragma unroll
    for (int j = 0; j < 4; ++j) {
        float v = acc[j];
        const int row = m * 16 + g * 4 + j, col = n * 16 + l15;
        unsigned hv = pk2(v, 0.f);
        float hf = lo_f(hv);
        unsigned lv = pk2(v - hf, 0.f);
        uh[(size_t)row * F_ + col] = (ushort_t)hv;
        ul[(size_t)row * F_ + col] = (ushort_t)lv;
    }
}

// ---- k_cvt_sw: x -> pre-swizzled bf16 tiled layout -----------------------
__global__ __launch_bounds__(256)
void k_cvt_sw(const float* __restrict__ src, ushort_t* __restrict__ dst) {
    const int c = blockIdx.x * 256 + threadIdx.x;
    const int rg = c >> 7, kg = c & 127;
    const int t = kg >> 2, k8 = kg & 3;
    const float4* s4 = reinterpret_cast<const float4*>(src + (size_t)rg * F_ + t * 32 + k8 * 8);
    float4 v0 = s4[0], v1 = s4[1];
    uint4 o;
    o.x = pk2(v0.x, v0.y); o.y = pk2(v0.z, v0.w);
    o.z = pk2(v1.x, v1.y); o.w = pk2(v1.z, v1.w);
    const int rb = rg >> 7, r = rg & 127;
    size_t base = ((size_t)(rb * 32 + t)) * 8192;
    int off = (r * 64 + k8 * 16) ^ ((r & 7) << 4);
    *reinterpret_cast<uint4*>(reinterpret_cast<char*>(dst) + base + off) = o;
}

// ---- k_z_sqx2: sq_x via bf16 MFMA GEMM with global_load_lds --------------
__global__ __launch_bounds__(256)
void k_z_sqx2(const ushort_t* __restrict__ xh, const ushort_t* __restrict__ omh,
              float* __restrict__ sqx) {
    const int bx = blockIdx.x, by = blockIdx.y;
    __shared__ __align__(16) ushort_t sA[128 * 32];
    __shared__ __align__(16) ushort_t sB[128 * 32];
    const int tid = threadIdx.x;
    const int lane = tid & 63, w = tid >> 6;
    const int wr = (w >> 1) * 64, wc = (w & 1) * 64;
    const int l15 = lane & 15, g = lane >> 4;

    f32x4 acc[4][4] = {};
    const char* xb = reinterpret_cast<const char*>(xh) + (size_t)bx * 32 * 8192;
    const char* ob = reinterpret_cast<const char*>(omh) + (size_t)by * 32 * 8192;
    char* sAc = reinterpret_cast<char*>(sA);
    char* sBc = reinterpret_cast<char*>(sB);

    for (int t = 0; t < 32; ++t) {
        __syncthreads();
        gload16(xb + (size_t)t * 8192 + tid * 16,        sAc + tid * 16);
        gload16(xb + (size_t)t * 8192 + 4096 + tid * 16, sAc + 4096 + tid * 16);
        gload16(ob + (size_t)t * 8192 + tid * 16,        sBc + tid * 16);
        gload16(ob + (size_t)t * 8192 + 4096 + tid * 16, sBc + 4096 + tid * 16);
        __syncthreads();
        short8 a[4], b[4];
#pragma unroll
        for (int m = 0; m < 4; ++m) {
            int row = wr + m * 16 + l15;
            int off = (row * 64 + g * 16) ^ ((row & 7) << 4);
            a[m] = *reinterpret_cast<const short8*>(sAc + off);
        }
#pragma unroll
        for (int n = 0; n < 4; ++n) {
            int row = wc + n * 16 + l15;
            int off = (row * 64 + g * 16) ^ ((row & 7) << 4);
            b[n] = *reinterpret_cast<const short8*>(sBc + off);
        }
#pragma unroll
        for (int m = 0; m < 4; ++m)
#pragma unroll
            for (int n = 0; n < 4; ++n)
                acc[m][n] = __builtin_amdgcn_mfma_f32_16x16x32_bf16(a[m], b[n], acc[m][n], 0, 0, 0);
    }
#pragma unroll
    for (int m = 0; m < 4; ++m) {
#pragma unroll
        for (int j = 0; j < 4; ++j) {
            float s = 0.f;
#pragma unroll
            for (int n = 0; n < 4; ++n) { float v = acc[m][n][j]; s = fmaf(v, v, s); }
            s += __shfl_xor(s, 1); s += __shfl_xor(s, 2);
            s += __shfl_xor(s, 4); s += __shfl_xor(s, 8);
            if (l15 == 0) atomicAdd(&sqx[bx * 128 + wr + m * 16 + g * 4 + j], s);
        }
    }
}

// ---- k_z_sqx: fallback with inline convert -------------------------------
__global__ __launch_bounds__(256)
void k_z_sqx(const float* __restrict__ x, const float* __restrict__ om,
             float* __restrict__ sqx) {
    const int brow = blockIdx.x * 128;
    const int bcol = blockIdx.y * 128;
    __shared__ __align__(16) ushort_t sA[128 * 32];
    __shared__ __align__(16) ushort_t sB[128 * 32];
    const int tid = threadIdx.x;
    const int lane = tid & 63, w = tid >> 6;
    const int wr = (w >> 1) * 64, wc = (w & 1) * 64;
    const int l15 = lane & 15, g = lane >> 4;
    f32x4 acc[4][4] = {};
    for (int k0 = 0; k0 < F_; k0 += 32) {
        __syncthreads();
#pragma unroll
        for (int j = 0; j < 4; ++j) {
            int idx = tid + j * 256;
            int row = idx >> 3, c4 = idx & 7;
            float4 va = *reinterpret_cast<const float4*>(x  + (size_t)(brow + row) * F_ + k0 + c4 * 4);
            float4 vb = *reinterpret_cast<const float4*>(om + (size_t)(bcol + row) * F_ + k0 + c4 * 4);
            int off = (row * 64 + c4 * 8) ^ ((row & 7) << 4);
            *reinterpret_cast<uint2*>(reinterpret_cast<char*>(sA) + off) =
                make_uint2(pk2(va.x, va.y), pk2(va.z, va.w));
            *reinterpret_cast<uint2*>(reinterpret_cast<char*>(sB) + off) =
                make_uint2(pk2(vb.x, vb.y), pk2(vb.z, vb.w));
        }
        __syncthreads();
        short8 a[4], b[4];
#pragma unroll
        for (int m = 0; m < 4; ++m) {
            int row = wr + m * 16 + l15;
            int off = (row * 64 + g * 16) ^ ((row & 7) << 4);
            a[m] = *reinterpret_cast<const short8*>(reinterpret_cast<const char*>(sA) + off);
        }
#pragma unroll
        for (int n = 0; n < 4; ++n) {
            int row = wc + n * 16 + l15;
            int off = (row * 64 + g * 16) ^ ((row & 7) << 4);
            b[n] = *reinterpret_cast<const short8*>(reinterpret_cast<const char*>(sB) + off);
        }
#pragma unroll
        for (int m = 0; m < 4; ++m)
#pragma unroll
            for (int n = 0; n < 4; ++n)
                acc[m][n] = __builtin_amdgcn_mfma_f32_16x16x32_bf16(a[m], b[n], acc[m][n], 0, 0, 0);
    }
#pragma unroll
    for (int m = 0; m < 4; ++m) {
#pragma unroll
        for (int j = 0; j < 4; ++j) {
            float s = 0.f;
#pragma unroll
            for (int n = 0; n < 4; ++n) { float v = acc[m][n][j]; s = fmaf(v, v, s); }
            s += __shfl_xor(s, 1); s += __shfl_xor(s, 2);
            s += __shfl_xor(s, 4); s += __shfl_xor(s, 8);
            if (l15 == 0) atomicAdd(&sqx[brow + wr + m * 16 + g * 4 + j], s);
        }
    }
}

// ---- k_dist3: single-term bf16 cross, xh from swizzled layout ------------
// grid 512, block 256 (4 waves K-split 256 each), M-tile 16, N = 160.
__global__ __launch_bounds__(256)
void k_dist3(const ushort_t* __restrict__ xh, const ushort_t* __restrict__ uh,
             const float* __restrict__ sqx, const float* __restrict__ sqp,
             float* __restrict__ dist, float* __restrict__ pred) {
    const int brow = blockIdx.x * 16;
    const int tid = threadIdx.x, lane = tid & 63, w = tid >> 6;
    const int l15 = lane & 15, g = lane >> 4;
    __shared__ float red[4][10][16][16];

    f32x4 acc[10] = {};
    // xh pre-swizzled layout: tile (rb*32 + t32)*8192 bytes, within-tile
    // byte = (r*64 + g*16) ^ ((r&7)<<4); t32 = w*8 + ks.
    const int rb = brow >> 7, r = (brow & 127) + l15;
    const char* xb = reinterpret_cast<const char*>(xh) +
                     ((size_t)(rb * 32 + w * 8)) * 8192 +
                     (((r * 64 + g * 16)) ^ ((r & 7) << 4));
    const ushort_t* buh = uh + (size_t)l15 * F_ + w * 256 + g * 8;

#pragma unroll
    for (int ks = 0; ks < 8; ++ks) {
        short8 ah = *reinterpret_cast<const short8*>(xb + (size_t)ks * 8192);
#pragma unroll
        for (int f = 0; f < 10; ++f) {
            short8 bh = *reinterpret_cast<const short8*>(buh + (size_t)f * 16 * F_ + ks * 32);
            acc[f] = __builtin_amdgcn_mfma_f32_16x16x32_bf16(ah, bh, acc[f], 0, 0, 0);
        }
    }

    // store with XOR'd col (l15^g) to spread banks; read side applies n^(m>>2)
#pragma unroll
    for (int f = 0; f < 10; ++f)
#pragma unroll
        for (int j = 0; j < 4; ++j) red[w][f][g * 4 + j][l15 ^ g] = acc[f][j];
    __syncthreads();

    const int m = tid >> 4, n = tid & 15;
    const int row = brow + m;
    const int nn = n ^ (m >> 2);
    float sx = sqx[row];
    float best = 3.4e38f; int bi = 0;
#pragma unroll
    for (int f = 0; f < 10; ++f) {
        float d = red[0][f][m][nn] + red[1][f][m][nn] + red[2][f][m][nn] + red[3][f][m][nn];
        float dv = sx + sqp[f * 16 + n] - 2.f * d;
        dist[(size_t)row * P_ + f * 16 + n] = dv;
        float mn = dv;
        mn = fminf(mn, __shfl_xor(mn, 1));
        mn = fminf(mn, __shfl_xor(mn, 2));
        mn = fminf(mn, __shfl_xor(mn, 4));
        mn = fminf(mn, __shfl_xor(mn, 8));
        if (mn < best) { best = mn; bi = f; }   // strict '<' => first min
    }
    if (n == 0) pred[row] = (float)bi;
}

// ---- k_dist2: tier-1 fallback (f32 x, inline hi-convert, 1-term) ---------
__global__ __launch_bounds__(256)
void k_dist2(const float* __restrict__ x, const ushort_t* __restrict__ uh,
             const float* __restrict__ sqx, const float* __restrict__ sqp,
             float* __restrict__ dist, float* __restrict__ pred) {
    const int brow = blockIdx.x * 16;
    const int tid = threadIdx.x, lane = tid & 63, w = tid >> 6;
    const int l15 = lane & 15, g = lane >> 4;
    __shared__ float red[4][10][16][16];

    f32x4 acc[10] = {};
    const float* xp = x + (size_t)(brow + l15) * F_ + w * 256 + g * 8;
    const ushort_t* buh = uh + (size_t)l15 * F_ + w * 256 + g * 8;

#pragma unroll 2
    for (int ks = 0; ks < 8; ++ks) {
        float4 v0 = *reinterpret_cast<const float4*>(xp + ks * 32);
        float4 v1 = *reinterpret_cast<const float4*>(xp + ks * 32 + 4);
        union { unsigned u[4]; short8 s; } cva;
        cva.u[0] = pk2(v0.x, v0.y); cva.u[1] = pk2(v0.z, v0.w);
        cva.u[2] = pk2(v1.x, v1.y); cva.u[3] = pk2(v1.z, v1.w);
        short8 ah = cva.s;
#pragma unroll
        for (int f = 0; f < 10; ++f) {
            short8 bh = *reinterpret_cast<const short8*>(buh + (size_t)f * 16 * F_ + ks * 32);
            acc[f] = __builtin_amdgcn_mfma_f32_16x16x32_bf16(ah, bh, acc[f], 0, 0, 0);
        }
    }
#pragma unroll
    for (int f = 0; f < 10; ++f)
#pragma unroll
        for (int j = 0; j < 4; ++j) red[w][f][g * 4 + j][l15 ^ g] = acc[f][j];
    __syncthreads();
    const int m = tid >> 4, n = tid & 15;
    const int row = brow + m;
    const int nn = n ^ (m >> 2);
    float sx = sqx[row];
    float best = 3.4e38f; int bi = 0;
#pragma unroll
    for (int f = 0; f < 10; ++f) {
        float d = red[0][f][m][nn] + red[1][f][m][nn] + red[2][f][m][nn] + red[3][f][m][nn];
        float dv = sx + sqp[f * 16 + n] - 2.f * d;
        dist[(size_t)row * P_ + f * 16 + n] = dv;
        float mn = dv;
        mn = fminf(mn, __shfl_xor(mn, 1));
        mn = fminf(mn, __shfl_xor(mn, 2));
        mn = fminf(mn, __shfl_xor(mn, 4));
        mn = fminf(mn, __shfl_xor(mn, 8));
        if (mn < best) { best = mn; bi = f; }
    }
    if (n == 0) pred[row] = (float)bi;
}

// ---- tier-0 fallback kernels (R3 path) -----------------------------------

__global__ __launch_bounds__(256)
void k_proj(const float* __restrict__ prot, const float* __restrict__ om,
            float* __restrict__ zp, float* __restrict__ sqp) {
    const int n0 = blockIdx.x * 16;
    const int tid = threadIdx.x, lane = tid & 63, w = tid >> 6;
    const int l15 = lane & 15, g = lane >> 4;
    __shared__ float red[4][10][16][16];
    f32x4 acc[10] = {};
    const float* op = om   + (size_t)(n0 + l15) * F_ + w * 256 + g * 8;
    const float* pp = prot + (size_t)l15 * F_ + w * 256 + g * 8;
#pragma unroll 2
    for (int ks = 0; ks < 8; ++ks) {
        float4 b0 = *reinterpret_cast<const float4*>(op + ks * 32);
        float4 b1 = *reinterpret_cast<const float4*>(op + ks * 32 + 4);
        union { unsigned u[4]; short8 s; } cbh, cbl;
        cbh.u[0] = pk2(b0.x, b0.y); cbh.u[1] = pk2(b0.z, b0.w);
        cbh.u[2] = pk2(b1.x, b1.y); cbh.u[3] = pk2(b1.z, b1.w);
        cbl.u[0] = pk2(b0.x - lo_f(cbh.u[0]), b0.y - hi_f(cbh.u[0]));
        cbl.u[1] = pk2(b0.z - lo_f(cbh.u[1]), b0.w - hi_f(cbh.u[1]));
        cbl.u[2] = pk2(b1.x - lo_f(cbh.u[2]), b1.y - hi_f(cbh.u[2]));
        cbl.u[3] = pk2(b1.z - lo_f(cbh.u[3]), b1.w - hi_f(cbh.u[3]));
        short8 bh = cbh.s, bl = cbl.s;
#pragma unroll
        for (int f = 0; f < 10; ++f) {
            float4 a0 = *reinterpret_cast<const float4*>(pp + (size_t)f * 16 * F_ + ks * 32);
            float4 a1 = *reinterpret_cast<const float4*>(pp + (size_t)f * 16 * F_ + ks * 32 + 4);
            union { unsigned u[4]; short8 s; } cah, cal;
            cah.u[0] = pk2(a0.x, a0.y); cah.u[1] = pk2(a0.z, a0.w);
            cah.u[2] = pk2(a1.x, a1.y); cah.u[3] = pk2(a1.z, a1.w);
            cal.u[0] = pk2(a0.x - lo_f(cah.u[0]), a0.y - hi_f(cah.u[0]));
            cal.u[1] = pk2(a0.z - lo_f(cah.u[1]), a0.w - hi_f(cah.u[1]));
            cal.u[2] = pk2(a1.x - lo_f(cah.u[2]), a1.y - hi_f(cah.u[2]));
            cal.u[3] = pk2(a1.z - lo_f(cah.u[3]), a1.w - hi_f(cah.u[3]));
            acc[f] = __builtin_amdgcn_mfma_f32_16x16x32_bf16(cah.s, bh, acc[f], 0, 0, 0);
            acc[f] = __builtin_amdgcn_mfma_f32_16x16x32_bf16(cal.s, bh, acc[f], 0, 0, 0);
            acc[f] = __builtin_amdgcn_mfma_f32_16x16x32_bf16(cah.s, bl, acc[f], 0, 0, 0);
        }
    }
#pragma unroll
    for (int f = 0; f < 10; ++f)
#pragma unroll
        for (int j = 0; j < 4; ++j) red[w][f][g * 4 + j][l15] = acc[f][j];
    __syncthreads();
    if (tid < 160) {
        const int f = tid >> 4, m = tid & 15;
        float s = 0.f;
#pragma unroll
        for (int n = 0; n < 16; ++n) {
            float v = red[0][f][m][n] + red[1][f][m][n] + red[2][f][m][n] + red[3][f][m][n];
            zp[(size_t)tid * F_ + n0 + n] = v;
            s = fmaf(v, v, s);
        }
        atomicAdd(&sqp[tid], s);
    }
}

__global__ __launch_bounds__(128)
void k_u(const float* __restrict__ zp, const float* __restrict__ om,
         float* __restrict__ u) {
    const int c  = blockIdx.x * 128 + threadIdx.x;
    const int r0 = blockIdx.y * 32;
    const int kz = blockIdx.z * 128;
    __shared__ __align__(16) float zt[128][36];
    for (int i = threadIdx.x; i < 128 * 32; i += 128) {
        int k = i >> 5, r = i & 31;
        zt[k][r] = zp[(size_t)(r0 + r) * F_ + kz + k];
    }
    __syncthreads();
    float acc[32];
#pragma unroll
    for (int r = 0; r < 32; ++r) acc[r] = 0.f;
    for (int k = 0; k < 128; ++k) {
        float o = om[(size_t)(kz + k) * F_ + c];
        const float4* zr = reinterpret_cast<const float4*>(&zt[k][0]);
#pragma unroll
        for (int r4 = 0; r4 < 8; ++r4) {
            float4 z4 = zr[r4];
            acc[r4 * 4 + 0] = fmaf(z4.x, o, acc[r4 * 4 + 0]);
            acc[r4 * 4 + 1] = fmaf(z4.y, o, acc[r4 * 4 + 1]);
            acc[r4 * 4 + 2] = fmaf(z4.z, o, acc[r4 * 4 + 2]);
            acc[r4 * 4 + 3] = fmaf(z4.w, o, acc[r4 * 4 + 3]);
        }
    }
#pragma unroll
    for (int r = 0; r < 32; ++r) atomicAdd(&u[(size_t)(r0 + r) * F_ + c], acc[r]);
}

__global__ __launch_bounds__(256)
void k_usplit(const float* __restrict__ u, ushort_t* __restrict__ uh,
              ushort_t* __restrict__ ul) {
    const int b = blockIdx.x, t = threadIdx.x;
    float4 v = *reinterpret_cast<const float4*>(u + (size_t)b * F_ + t * 4);
    unsigned h0 = pk2(v.x, v.y), h1 = pk2(v.z, v.w);
    unsigned q0 = pk2(v.x - lo_f(h0), v.y - hi_f(h0));
    unsigned q1 = pk2(v.z - lo_f(h1), v.w - hi_f(h1));
    *reinterpret_cast<uint2*>(uh + (size_t)b * F_ + t * 4) = make_uint2(h0, h1);
    *reinterpret_cast<uint2*>(ul + (size_t)b * F_ + t * 4) = make_uint2(q0, q1);
}

// ---- launch --------------------------------------------------------------

extern "C" void kernel_launch(void* const* d_in, const int* in_sizes, int n_in,
                              void* d_out, int out_size, void* d_ws, size_t ws_size,
                              hipStream_t stream) {
    (void)in_sizes; (void)n_in; (void)out_size;
    const float* x    = (const float*)d_in[0];
    const float* prot = (const float*)d_in[1];
    const float* om   = (const float*)d_in[2];

    float* out  = (float*)d_out;
    float* dist = out;
    float* pred = out + (size_t)B_ * P_;

    char* W = (char*)d_ws;
    float* sqx = (float*)W;                    // 32768 B
    float* sqp = (float*)(W + 32768);          // 1024 B
    size_t o = 33792;
    ushort_t* phl   = (ushort_t*)(W + o); o += 327680;
    ushort_t* pll   = (ushort_t*)(W + o); o += 327680;
    ushort_t* zph   = (ushort_t*)(W + o); o += 327680;
    ushort_t* zpl   = (ushort_t*)(W + o); o += 327680;
    ushort_t* uh    = (ushort_t*)(W + o); o += 327680;
    ushort_t* ul    = (ushort_t*)(W + o); o += 327680;
    ushort_t* omh_r = (ushort_t*)(W + o); o += 2097152;
    ushort_t* oml_r = (ushort_t*)(W + o); o += 2097152;
    ushort_t* omTh  = (ushort_t*)(W + o); o += 2097152;
    ushort_t* omTl  = (ushort_t*)(W + o); o += 2097152;
    ushort_t* omh_sw= (ushort_t*)(W + o); o += 2097152;   // ~12.49 MB so far
    ushort_t* xh    = (ushort_t*)(W + o);                 // +16 MB -> ~29.3 MB

    const int tier = (ws_size >= (size_t)30 * 1024 * 1024) ? 2
                   : (ws_size >= (size_t)13 * 1024 * 1024) ? 1 : 0;

    hipMemsetAsync(W, 0, 33792, stream);   // sqx + sqp together

    if (tier >= 1) {
        k_prep1<<<266, 256, 0, stream>>>(om, prot, omh_r, oml_r, omTh, omTl,
                                         omh_sw, phl, pll);
        k_zp2  <<<160, 256, 0, stream>>>(phl, pll, omh_r, oml_r, zph, zpl, sqp);
        k_u2   <<<160, 256, 0, stream>>>(zph, zpl, omTh, omTl, uh, ul);
        if (tier == 2) {
            k_cvt_sw<<<4096, 256, 0, stream>>>(x, xh);
            k_z_sqx2<<<dim3(64, 8), 256, 0, stream>>>(xh, omh_sw, sqx);
            k_dist3<<<512, 256, 0, stream>>>(xh, uh, sqx, sqp, dist, pred);
        } else {
            k_z_sqx <<<dim3(64, 8), 256, 0, stream>>>(x, om, sqx);
            k_dist2<<<512, 256, 0, stream>>>(x, uh, sqx, sqp, dist, pred);
        }
    } else {
        // tier-0: R3 path (ws >= ~1.35 MB known-good)
        float* wsf = (float*)d_ws;
        float* zp  = wsf + 8448;
        float* u   = wsf + 172288;
        ushort_t* uh0 = (ushort_t*)(wsf + 8448);
        ushort_t* ul0 = uh0 + 163840;
        hipMemsetAsync(u, 0, (size_t)P_ * F_ * sizeof(float), stream);
        k_proj  <<<64, 256, 0, stream>>>(prot, om, zp, sqp);
        k_u     <<<dim3(8, 5, 8), 128, 0, stream>>>(zp, om, u);
        k_usplit<<<160, 256, 0, stream>>>(u, uh0, ul0);
        k_z_sqx <<<dim3(64, 8), 256, 0, stream>>>(x, om, sqx);
        k_dist2 <<<512, 256, 0, stream>>>(x, uh0, sqx, sqp, dist, pred);
    }
}

// Round 6
// 111.962 us; speedup vs baseline: 2.1320x; 1.0361x over previous
//
#include <hip/hip_runtime.h>
#include <hip/hip_bf16.h>

#define B_ 8192
#define F_ 1024
#define P_ 160
#define C_ 10

typedef __attribute__((ext_vector_type(8))) short short8;
typedef __attribute__((ext_vector_type(4))) float f32x4;
typedef unsigned short ushort_t;

// ---- helpers -------------------------------------------------------------

__device__ inline unsigned pk2(float a, float b) {
    __hip_bfloat162 h = __float22bfloat162_rn(make_float2(a, b));
    return *reinterpret_cast<unsigned*>(&h);
}
__device__ inline float lo_f(unsigned u) { return __uint_as_float(u << 16); }
__device__ inline float hi_f(unsigned u) { return __uint_as_float(u & 0xffff0000u); }

__device__ inline void gload16(const void* g, void* l) {
    __builtin_amdgcn_global_load_lds((const __attribute__((address_space(1))) unsigned*)g,
                                     (__attribute__((address_space(3))) unsigned*)l, 16, 0, 0);
}

// ---- k_prep1: all operand conversions in one pass + zero-init ------------
// blocks 0..255: om tiles; blocks 256..265: prot; block 266: zero sqx+sqp
// (replaces hipMemsetAsync: the runtime's 33KB fill kernel cost ~41us/replay).
__global__ __launch_bounds__(256)
void k_prep1(const float* __restrict__ om, const float* __restrict__ prot,
             ushort_t* __restrict__ omh_r, ushort_t* __restrict__ oml_r,
             ushort_t* __restrict__ omTh, ushort_t* __restrict__ omTl,
             ushort_t* __restrict__ omh_sw,
             ushort_t* __restrict__ phl, ushort_t* __restrict__ pll,
             float4* __restrict__ zero_dst) {
    const int bid = blockIdx.x, tid = threadIdx.x;
    if (bid < 256) {
        const int tr = bid >> 4, tc = bid & 15;
        __shared__ float tile[64][65];
        const int r0 = tid >> 4, cq = (tid & 15) * 4;
#pragma unroll
        for (int i = 0; i < 4; ++i) {
            const int row = r0 + i * 16;
            const int gr = tr * 64 + row;
            float4 v = *reinterpret_cast<const float4*>(om + (size_t)gr * F_ + tc * 64 + cq);
            tile[row][cq + 0] = v.x; tile[row][cq + 1] = v.y;
            tile[row][cq + 2] = v.z; tile[row][cq + 3] = v.w;
            unsigned h0 = pk2(v.x, v.y), h1 = pk2(v.z, v.w);
            unsigned l0 = pk2(v.x - lo_f(h0), v.y - hi_f(h0));
            unsigned l1 = pk2(v.z - lo_f(h1), v.w - hi_f(h1));
            size_t ro = (size_t)gr * F_ + tc * 64 + cq;
            *reinterpret_cast<uint2*>(omh_r + ro) = make_uint2(h0, h1);
            *reinterpret_cast<uint2*>(oml_r + ro) = make_uint2(l0, l1);
            const int rb = gr >> 7, r = gr & 127;
            const int c0 = tc * 64 + cq;
            const int t32 = c0 >> 5, k8 = (c0 >> 3) & 3, half = (c0 >> 2) & 1;
            size_t base = ((size_t)(rb * 32 + t32)) * 8192;
            int off = (r * 64 + k8 * 16) ^ ((r & 7) << 4);
            *reinterpret_cast<uint2*>(reinterpret_cast<char*>(omh_sw) + base + off + half * 8) =
                make_uint2(h0, h1);
        }
        __syncthreads();
#pragma unroll
        for (int i = 0; i < 4; ++i) {
            const int rowT = r0 + i * 16;
            float a = tile[cq + 0][rowT], b = tile[cq + 1][rowT];
            float c = tile[cq + 2][rowT], d = tile[cq + 3][rowT];
            unsigned h0 = pk2(a, b), h1 = pk2(c, d);
            unsigned l0 = pk2(a - lo_f(h0), b - hi_f(h0));
            unsigned l1 = pk2(c - lo_f(h1), d - hi_f(h1));
            size_t to = (size_t)(tc * 64 + rowT) * F_ + tr * 64 + cq;
            *reinterpret_cast<uint2*>(omTh + to) = make_uint2(h0, h1);
            *reinterpret_cast<uint2*>(omTl + to) = make_uint2(l0, l1);
        }
    } else if (bid < 266) {
        const int pb = bid - 256;
        const int row = pb * 16 + (tid >> 4);
#pragma unroll
        for (int i = 0; i < 16; ++i) {
            const int col = (tid & 15) * 4 + i * 64;
            float4 v = *reinterpret_cast<const float4*>(prot + (size_t)row * F_ + col);
            unsigned h0 = pk2(v.x, v.y), h1 = pk2(v.z, v.w);
            unsigned l0 = pk2(v.x - lo_f(h0), v.y - hi_f(h0));
            unsigned l1 = pk2(v.z - lo_f(h1), v.w - hi_f(h1));
            size_t ro = (size_t)row * F_ + col;
            *reinterpret_cast<uint2*>(phl + ro) = make_uint2(h0, h1);
            *reinterpret_cast<uint2*>(pll + ro) = make_uint2(l0, l1);
        }
    } else {
        // zero sqx (8192 f32) + sqp (256 f32) = 2112 float4
        const float4 z = make_float4(0.f, 0.f, 0.f, 0.f);
        for (int i = tid; i < 2112; i += 256) zero_dst[i] = z;
    }
}

// ---- k_zp2: zp = prot @ om^T (split operands), fused sqp -----------------
__global__ __launch_bounds__(256)
void k_zp2(const ushort_t* __restrict__ phl, const ushort_t* __restrict__ pll,
           const ushort_t* __restrict__ omh_r, const ushort_t* __restrict__ oml_r,
           ushort_t* __restrict__ zph, ushort_t* __restrict__ zpl,
           float* __restrict__ sqp) {
    const int tid = threadIdx.x, lane = tid & 63, w = tid >> 6;
    const int fid = blockIdx.x * 4 + w;
    const int m = fid >> 6, n = fid & 63;
    const int l15 = lane & 15, g = lane >> 4;

    f32x4 acc = {};
    const ushort_t* pa_h = phl + (size_t)(m * 16 + l15) * F_ + g * 8;
    const ushort_t* pa_l = pll + (size_t)(m * 16 + l15) * F_ + g * 8;
    const ushort_t* pb_h = omh_r + (size_t)(n * 16 + l15) * F_ + g * 8;
    const ushort_t* pb_l = oml_r + (size_t)(n * 16 + l15) * F_ + g * 8;
#pragma unroll 4
    for (int ks = 0; ks < 32; ++ks) {
        short8 ah = *reinterpret_cast<const short8*>(pa_h + ks * 32);
        short8 al = *reinterpret_cast<const short8*>(pa_l + ks * 32);
        short8 bh = *reinterpret_cast<const short8*>(pb_h + ks * 32);
        short8 bl = *reinterpret_cast<const short8*>(pb_l + ks * 32);
        acc = __builtin_amdgcn_mfma_f32_16x16x32_bf16(ah, bh, acc, 0, 0, 0);
        acc = __builtin_amdgcn_mfma_f32_16x16x32_bf16(al, bh, acc, 0, 0, 0);
        acc = __builtin_amdgcn_mfma_f32_16x16x32_bf16(ah, bl, acc, 0, 0, 0);
    }
#pragma unroll
    for (int j = 0; j < 4; ++j) {
        float v = acc[j];
        const int row = m * 16 + g * 4 + j, col = n * 16 + l15;
        unsigned hv = pk2(v, 0.f);
        float hf = lo_f(hv);
        unsigned lv = pk2(v - hf, 0.f);
        zph[(size_t)row * F_ + col] = (ushort_t)hv;
        zpl[(size_t)row * F_ + col] = (ushort_t)lv;
        float s = v * v;
        s += __shfl_xor(s, 1); s += __shfl_xor(s, 2);
        s += __shfl_xor(s, 4); s += __shfl_xor(s, 8);
        if (l15 == 0) atomicAdd(&sqp[row], s);
    }
}

// ---- k_u2: u = zp @ om (via omT splits) ----------------------------------
__global__ __launch_bounds__(256)
void k_u2(const ushort_t* __restrict__ zph, const ushort_t* __restrict__ zpl,
          const ushort_t* __restrict__ omTh, const ushort_t* __restrict__ omTl,
          ushort_t* __restrict__ uh, ushort_t* __restrict__ ul) {
    const int tid = threadIdx.x, lane = tid & 63, w = tid >> 6;
    const int fid = blockIdx.x * 4 + w;
    const int m = fid >> 6, n = fid & 63;
    const int l15 = lane & 15, g = lane >> 4;

    f32x4 acc = {};
    const ushort_t* pa_h = zph + (size_t)(m * 16 + l15) * F_ + g * 8;
    const ushort_t* pa_l = zpl + (size_t)(m * 16 + l15) * F_ + g * 8;
    const ushort_t* pb_h = omTh + (size_t)(n * 16 + l15) * F_ + g * 8;
    const ushort_t* pb_l = omTl + (size_t)(n * 16 + l15) * F_ + g * 8;
#pragma unroll 4
    for (int ks = 0; ks < 32; ++ks) {
        short8 ah = *reinterpret_cast<const short8*>(pa_h + ks * 32);
        short8 al = *reinterpret_cast<const short8*>(pa_l + ks * 32);
        short8 bh = *reinterpret_cast<const short8*>(pb_h + ks * 32);
        short8 bl = *reinterpret_cast<const short8*>(pb_l + ks * 32);
        acc = __builtin_amdgcn_mfma_f32_16x16x32_bf16(ah, bh, acc, 0, 0, 0);
        acc = __builtin_amdgcn_mfma_f32_16x16x32_bf16(al, bh, acc, 0, 0, 0);
        acc = __builtin_amdgcn_mfma_f32_16x16x32_bf16(ah, bl, acc, 0, 0, 0);
    }
#pragma unroll
    for (int j = 0; j < 4; ++j) {
        float v = acc[j];
        const int row = m * 16 + g * 4 + j, col = n * 16 + l15;
        unsigned hv = pk2(v, 0.f);
        float hf = lo_f(hv);
        unsigned lv = pk2(v - hf, 0.f);
        uh[(size_t)row * F_ + col] = (ushort_t)hv;
        ul[(size_t)row * F_ + col] = (ushort_t)lv;
    }
}

// ---- k_cvt_sw: x -> pre-swizzled bf16 tiled layout -----------------------
__global__ __launch_bounds__(256)
void k_cvt_sw(const float* __restrict__ src, ushort_t* __restrict__ dst) {
    const int c = blockIdx.x * 256 + threadIdx.x;
    const int rg = c >> 7, kg = c & 127;
    const int t = kg >> 2, k8 = kg & 3;
    const float4* s4 = reinterpret_cast<const float4*>(src + (size_t)rg * F_ + t * 32 + k8 * 8);
    float4 v0 = s4[0], v1 = s4[1];
    uint4 o;
    o.x = pk2(v0.x, v0.y); o.y = pk2(v0.z, v0.w);
    o.z = pk2(v1.x, v1.y); o.w = pk2(v1.z, v1.w);
    const int rb = rg >> 7, r = rg & 127;
    size_t base = ((size_t)(rb * 32 + t)) * 8192;
    int off = (r * 64 + k8 * 16) ^ ((r & 7) << 4);
    *reinterpret_cast<uint4*>(reinterpret_cast<char*>(dst) + base + off) = o;
}

// ---- k_z_sqx2: sq_x via bf16 MFMA GEMM with global_load_lds --------------
__global__ __launch_bounds__(256)
void k_z_sqx2(const ushort_t* __restrict__ xh, const ushort_t* __restrict__ omh,
              float* __restrict__ sqx) {
    const int bx = blockIdx.x, by = blockIdx.y;
    __shared__ __align__(16) ushort_t sA[128 * 32];
    __shared__ __align__(16) ushort_t sB[128 * 32];
    const int tid = threadIdx.x;
    const int lane = tid & 63, w = tid >> 6;
    const int wr = (w >> 1) * 64, wc = (w & 1) * 64;
    const int l15 = lane & 15, g = lane >> 4;

    f32x4 acc[4][4] = {};
    const char* xb = reinterpret_cast<const char*>(xh) + (size_t)bx * 32 * 8192;
    const char* ob = reinterpret_cast<const char*>(omh) + (size_t)by * 32 * 8192;
    char* sAc = reinterpret_cast<char*>(sA);
    char* sBc = reinterpret_cast<char*>(sB);

    for (int t = 0; t < 32; ++t) {
        __syncthreads();
        gload16(xb + (size_t)t * 8192 + tid * 16,        sAc + tid * 16);
        gload16(xb + (size_t)t * 8192 + 4096 + tid * 16, sAc + 4096 + tid * 16);
        gload16(ob + (size_t)t * 8192 + tid * 16,        sBc + tid * 16);
        gload16(ob + (size_t)t * 8192 + 4096 + tid * 16, sBc + 4096 + tid * 16);
        __syncthreads();
        short8 a[4], b[4];
#pragma unroll
        for (int m = 0; m < 4; ++m) {
            int row = wr + m * 16 + l15;
            int off = (row * 64 + g * 16) ^ ((row & 7) << 4);
            a[m] = *reinterpret_cast<const short8*>(sAc + off);
        }
#pragma unroll
        for (int n = 0; n < 4; ++n) {
            int row = wc + n * 16 + l15;
            int off = (row * 64 + g * 16) ^ ((row & 7) << 4);
            b[n] = *reinterpret_cast<const short8*>(sBc + off);
        }
#pragma unroll
        for (int m = 0; m < 4; ++m)
#pragma unroll
            for (int n = 0; n < 4; ++n)
                acc[m][n] = __builtin_amdgcn_mfma_f32_16x16x32_bf16(a[m], b[n], acc[m][n], 0, 0, 0);
    }
#pragma unroll
    for (int m = 0; m < 4; ++m) {
#pragma unroll
        for (int j = 0; j < 4; ++j) {
            float s = 0.f;
#pragma unroll
            for (int n = 0; n < 4; ++n) { float v = acc[m][n][j]; s = fmaf(v, v, s); }
            s += __shfl_xor(s, 1); s += __shfl_xor(s, 2);
            s += __shfl_xor(s, 4); s += __shfl_xor(s, 8);
            if (l15 == 0) atomicAdd(&sqx[bx * 128 + wr + m * 16 + g * 4 + j], s);
        }
    }
}

// ---- k_z_sqx: fallback with inline convert -------------------------------
__global__ __launch_bounds__(256)
void k_z_sqx(const float* __restrict__ x, const float* __restrict__ om,
             float* __restrict__ sqx) {
    const int brow = blockIdx.x * 128;
    const int bcol = blockIdx.y * 128;
    __shared__ __align__(16) ushort_t sA[128 * 32];
    __shared__ __align__(16) ushort_t sB[128 * 32];
    const int tid = threadIdx.x;
    const int lane = tid & 63, w = tid >> 6;
    const int wr = (w >> 1) * 64, wc = (w & 1) * 64;
    const int l15 = lane & 15, g = lane >> 4;
    f32x4 acc[4][4] = {};
    for (int k0 = 0; k0 < F_; k0 += 32) {
        __syncthreads();
#pragma unroll
        for (int j = 0; j < 4; ++j) {
            int idx = tid + j * 256;
            int row = idx >> 3, c4 = idx & 7;
            float4 va = *reinterpret_cast<const float4*>(x  + (size_t)(brow + row) * F_ + k0 + c4 * 4);
            float4 vb = *reinterpret_cast<const float4*>(om + (size_t)(bcol + row) * F_ + k0 + c4 * 4);
            int off = (row * 64 + c4 * 8) ^ ((row & 7) << 4);
            *reinterpret_cast<uint2*>(reinterpret_cast<char*>(sA) + off) =
                make_uint2(pk2(va.x, va.y), pk2(va.z, va.w));
            *reinterpret_cast<uint2*>(reinterpret_cast<char*>(sB) + off) =
                make_uint2(pk2(vb.x, vb.y), pk2(vb.z, vb.w));
        }
        __syncthreads();
        short8 a[4], b[4];
#pragma unroll
        for (int m = 0; m < 4; ++m) {
            int row = wr + m * 16 + l15;
            int off = (row * 64 + g * 16) ^ ((row & 7) << 4);
            a[m] = *reinterpret_cast<const short8*>(reinterpret_cast<const char*>(sA) + off);
        }
#pragma unroll
        for (int n = 0; n < 4; ++n) {
            int row = wc + n * 16 + l15;
            int off = (row * 64 + g * 16) ^ ((row & 7) << 4);
            b[n] = *reinterpret_cast<const short8*>(reinterpret_cast<const char*>(sB) + off);
        }
#pragma unroll
        for (int m = 0; m < 4; ++m)
#pragma unroll
            for (int n = 0; n < 4; ++n)
                acc[m][n] = __builtin_amdgcn_mfma_f32_16x16x32_bf16(a[m], b[n], acc[m][n], 0, 0, 0);
    }
#pragma unroll
    for (int m = 0; m < 4; ++m) {
#pragma unroll
        for (int j = 0; j < 4; ++j) {
            float s = 0.f;
#pragma unroll
            for (int n = 0; n < 4; ++n) { float v = acc[m][n][j]; s = fmaf(v, v, s); }
            s += __shfl_xor(s, 1); s += __shfl_xor(s, 2);
            s += __shfl_xor(s, 4); s += __shfl_xor(s, 8);
            if (l15 == 0) atomicAdd(&sqx[brow + wr + m * 16 + g * 4 + j], s);
        }
    }
}

// ---- k_dist3: single-term bf16 cross, xh from swizzled layout ------------
__global__ __launch_bounds__(256)
void k_dist3(const ushort_t* __restrict__ xh, const ushort_t* __restrict__ uh,
             const float* __restrict__ sqx, const float* __restrict__ sqp,
             float* __restrict__ dist, float* __restrict__ pred) {
    const int brow = blockIdx.x * 16;
    const int tid = threadIdx.x, lane = tid & 63, w = tid >> 6;
    const int l15 = lane & 15, g = lane >> 4;
    __shared__ float red[4][10][16][16];

    f32x4 acc[10] = {};
    const int rb = brow >> 7, r = (brow & 127) + l15;
    const char* xb = reinterpret_cast<const char*>(xh) +
                     ((size_t)(rb * 32 + w * 8)) * 8192 +
                     (((r * 64 + g * 16)) ^ ((r & 7) << 4));
    const ushort_t* buh = uh + (size_t)l15 * F_ + w * 256 + g * 8;

#pragma unroll
    for (int ks = 0; ks < 8; ++ks) {
        short8 ah = *reinterpret_cast<const short8*>(xb + (size_t)ks * 8192);
#pragma unroll
        for (int f = 0; f < 10; ++f) {
            short8 bh = *reinterpret_cast<const short8*>(buh + (size_t)f * 16 * F_ + ks * 32);
            acc[f] = __builtin_amdgcn_mfma_f32_16x16x32_bf16(ah, bh, acc[f], 0, 0, 0);
        }
    }

#pragma unroll
    for (int f = 0; f < 10; ++f)
#pragma unroll
        for (int j = 0; j < 4; ++j) red[w][f][g * 4 + j][l15 ^ g] = acc[f][j];
    __syncthreads();

    const int m = tid >> 4, n = tid & 15;
    const int row = brow + m;
    const int nn = n ^ (m >> 2);
    float sx = sqx[row];
    float best = 3.4e38f; int bi = 0;
#pragma unroll
    for (int f = 0; f < 10; ++f) {
        float d = red[0][f][m][nn] + red[1][f][m][nn] + red[2][f][m][nn] + red[3][f][m][nn];
        float dv = sx + sqp[f * 16 + n] - 2.f * d;
        dist[(size_t)row * P_ + f * 16 + n] = dv;
        float mn = dv;
        mn = fminf(mn, __shfl_xor(mn, 1));
        mn = fminf(mn, __shfl_xor(mn, 2));
        mn = fminf(mn, __shfl_xor(mn, 4));
        mn = fminf(mn, __shfl_xor(mn, 8));
        if (mn < best) { best = mn; bi = f; }   // strict '<' => first min
    }
    if (n == 0) pred[row] = (float)bi;
}

// ---- k_dist2: tier-1 fallback (f32 x, inline hi-convert, 1-term) ---------
__global__ __launch_bounds__(256)
void k_dist2(const float* __restrict__ x, const ushort_t* __restrict__ uh,
             const float* __restrict__ sqx, const float* __restrict__ sqp,
             float* __restrict__ dist, float* __restrict__ pred) {
    const int brow = blockIdx.x * 16;
    const int tid = threadIdx.x, lane = tid & 63, w = tid >> 6;
    const int l15 = lane & 15, g = lane >> 4;
    __shared__ float red[4][10][16][16];

    f32x4 acc[10] = {};
    const float* xp = x + (size_t)(brow + l15) * F_ + w * 256 + g * 8;
    const ushort_t* buh = uh + (size_t)l15 * F_ + w * 256 + g * 8;

#pragma unroll 2
    for (int ks = 0; ks < 8; ++ks) {
        float4 v0 = *reinterpret_cast<const float4*>(xp + ks * 32);
        float4 v1 = *reinterpret_cast<const float4*>(xp + ks * 32 + 4);
        union { unsigned u[4]; short8 s; } cva;
        cva.u[0] = pk2(v0.x, v0.y); cva.u[1] = pk2(v0.z, v0.w);
        cva.u[2] = pk2(v1.x, v1.y); cva.u[3] = pk2(v1.z, v1.w);
        short8 ah = cva.s;
#pragma unroll
        for (int f = 0; f < 10; ++f) {
            short8 bh = *reinterpret_cast<const short8*>(buh + (size_t)f * 16 * F_ + ks * 32);
            acc[f] = __builtin_amdgcn_mfma_f32_16x16x32_bf16(ah, bh, acc[f], 0, 0, 0);
        }
    }
#pragma unroll
    for (int f = 0; f < 10; ++f)
#pragma unroll
        for (int j = 0; j < 4; ++j) red[w][f][g * 4 + j][l15 ^ g] = acc[f][j];
    __syncthreads();
    const int m = tid >> 4, n = tid & 15;
    const int row = brow + m;
    const int nn = n ^ (m >> 2);
    float sx = sqx[row];
    float best = 3.4e38f; int bi = 0;
#pragma unroll
    for (int f = 0; f < 10; ++f) {
        float d = red[0][f][m][nn] + red[1][f][m][nn] + red[2][f][m][nn] + red[3][f][m][nn];
        float dv = sx + sqp[f * 16 + n] - 2.f * d;
        dist[(size_t)row * P_ + f * 16 + n] = dv;
        float mn = dv;
        mn = fminf(mn, __shfl_xor(mn, 1));
        mn = fminf(mn, __shfl_xor(mn, 2));
        mn = fminf(mn, __shfl_xor(mn, 4));
        mn = fminf(mn, __shfl_xor(mn, 8));
        if (mn < best) { best = mn; bi = f; }
    }
    if (n == 0) pred[row] = (float)bi;
}

// ---- tier-0 fallback kernels (R3 path) -----------------------------------

__global__ __launch_bounds__(256)
void k_proj(const float* __restrict__ prot, const float* __restrict__ om,
            float* __restrict__ zp, float* __restrict__ sqp) {
    const int n0 = blockIdx.x * 16;
    const int tid = threadIdx.x, lane = tid & 63, w = tid >> 6;
    const int l15 = lane & 15, g = lane >> 4;
    __shared__ float red[4][10][16][16];
    f32x4 acc[10] = {};
    const float* op = om   + (size_t)(n0 + l15) * F_ + w * 256 + g * 8;
    const float* pp = prot + (size_t)l15 * F_ + w * 256 + g * 8;
#pragma unroll 2
    for (int ks = 0; ks < 8; ++ks) {
        float4 b0 = *reinterpret_cast<const float4*>(op + ks * 32);
        float4 b1 = *reinterpret_cast<const float4*>(op + ks * 32 + 4);
        union { unsigned u[4]; short8 s; } cbh, cbl;
        cbh.u[0] = pk2(b0.x, b0.y); cbh.u[1] = pk2(b0.z, b0.w);
        cbh.u[2] = pk2(b1.x, b1.y); cbh.u[3] = pk2(b1.z, b1.w);
        cbl.u[0] = pk2(b0.x - lo_f(cbh.u[0]), b0.y - hi_f(cbh.u[0]));
        cbl.u[1] = pk2(b0.z - lo_f(cbh.u[1]), b0.w - hi_f(cbh.u[1]));
        cbl.u[2] = pk2(b1.x - lo_f(cbh.u[2]), b1.y - hi_f(cbh.u[2]));
        cbl.u[3] = pk2(b1.z - lo_f(cbh.u[3]), b1.w - hi_f(cbh.u[3]));
        short8 bh = cbh.s, bl = cbl.s;
#pragma unroll
        for (int f = 0; f < 10; ++f) {
            float4 a0 = *reinterpret_cast<const float4*>(pp + (size_t)f * 16 * F_ + ks * 32);
            float4 a1 = *reinterpret_cast<const float4*>(pp + (size_t)f * 16 * F_ + ks * 32 + 4);
            union { unsigned u[4]; short8 s; } cah, cal;
            cah.u[0] = pk2(a0.x, a0.y); cah.u[1] = pk2(a0.z, a0.w);
            cah.u[2] = pk2(a1.x, a1.y); cah.u[3] = pk2(a1.z, a1.w);
            cal.u[0] = pk2(a0.x - lo_f(cah.u[0]), a0.y - hi_f(cah.u[0]));
            cal.u[1] = pk2(a0.z - lo_f(cah.u[1]), a0.w - hi_f(cah.u[1]));
            cal.u[2] = pk2(a1.x - lo_f(cah.u[2]), a1.y - hi_f(cah.u[2]));
            cal.u[3] = pk2(a1.z - lo_f(cah.u[3]), a1.w - hi_f(cah.u[3]));
            acc[f] = __builtin_amdgcn_mfma_f32_16x16x32_bf16(cah.s, bh, acc[f], 0, 0, 0);
            acc[f] = __builtin_amdgcn_mfma_f32_16x16x32_bf16(cal.s, bh, acc[f], 0, 0, 0);
            acc[f] = __builtin_amdgcn_mfma_f32_16x16x32_bf16(cah.s, bl, acc[f], 0, 0, 0);
        }
    }
#pragma unroll
    for (int f = 0; f < 10; ++f)
#pragma unroll
        for (int j = 0; j < 4; ++j) red[w][f][g * 4 + j][l15] = acc[f][j];
    __syncthreads();
    if (tid < 160) {
        const int f = tid >> 4, m = tid & 15;
        float s = 0.f;
#pragma unroll
        for (int n = 0; n < 16; ++n) {
            float v = red[0][f][m][n] + red[1][f][m][n] + red[2][f][m][n] + red[3][f][m][n];
            zp[(size_t)tid * F_ + n0 + n] = v;
            s = fmaf(v, v, s);
        }
        atomicAdd(&sqp[tid], s);
    }
}

__global__ __launch_bounds__(128)
void k_u(const float* __restrict__ zp, const float* __restrict__ om,
         float* __restrict__ u) {
    const int c  = blockIdx.x * 128 + threadIdx.x;
    const int r0 = blockIdx.y * 32;
    const int kz = blockIdx.z * 128;
    __shared__ __align__(16) float zt[128][36];
    for (int i = threadIdx.x; i < 128 * 32; i += 128) {
        int k = i >> 5, r = i & 31;
        zt[k][r] = zp[(size_t)(r0 + r) * F_ + kz + k];
    }
    __syncthreads();
    float acc[32];
#pragma unroll
    for (int r = 0; r < 32; ++r) acc[r] = 0.f;
    for (int k = 0; k < 128; ++k) {
        float o = om[(size_t)(kz + k) * F_ + c];
        const float4* zr = reinterpret_cast<const float4*>(&zt[k][0]);
#pragma unroll
        for (int r4 = 0; r4 < 8; ++r4) {
            float4 z4 = zr[r4];
            acc[r4 * 4 + 0] = fmaf(z4.x, o, acc[r4 * 4 + 0]);
            acc[r4 * 4 + 1] = fmaf(z4.y, o, acc[r4 * 4 + 1]);
            acc[r4 * 4 + 2] = fmaf(z4.z, o, acc[r4 * 4 + 2]);
            acc[r4 * 4 + 3] = fmaf(z4.w, o, acc[r4 * 4 + 3]);
        }
    }
#pragma unroll
    for (int r = 0; r < 32; ++r) atomicAdd(&u[(size_t)(r0 + r) * F_ + c], acc[r]);
}

__global__ __launch_bounds__(256)
void k_usplit(const float* __restrict__ u, ushort_t* __restrict__ uh,
              ushort_t* __restrict__ ul) {
    const int b = blockIdx.x, t = threadIdx.x;
    float4 v = *reinterpret_cast<const float4*>(u + (size_t)b * F_ + t * 4);
    unsigned h0 = pk2(v.x, v.y), h1 = pk2(v.z, v.w);
    unsigned q0 = pk2(v.x - lo_f(h0), v.y - hi_f(h0));
    unsigned q1 = pk2(v.z - lo_f(h1), v.w - hi_f(h1));
    *reinterpret_cast<uint2*>(uh + (size_t)b * F_ + t * 4) = make_uint2(h0, h1);
    *reinterpret_cast<uint2*>(ul + (size_t)b * F_ + t * 4) = make_uint2(q0, q1);
}

// ---- launch --------------------------------------------------------------

extern "C" void kernel_launch(void* const* d_in, const int* in_sizes, int n_in,
                              void* d_out, int out_size, void* d_ws, size_t ws_size,
                              hipStream_t stream) {
    (void)in_sizes; (void)n_in; (void)out_size;
    const float* x    = (const float*)d_in[0];
    const float* prot = (const float*)d_in[1];
    const float* om   = (const float*)d_in[2];

    float* out  = (float*)d_out;
    float* dist = out;
    float* pred = out + (size_t)B_ * P_;

    char* W = (char*)d_ws;
    float* sqx = (float*)W;                    // 32768 B
    float* sqp = (float*)(W + 32768);          // 1024 B
    size_t o = 33792;
    ushort_t* phl   = (ushort_t*)(W + o); o += 327680;
    ushort_t* pll   = (ushort_t*)(W + o); o += 327680;
    ushort_t* zph   = (ushort_t*)(W + o); o += 327680;
    ushort_t* zpl   = (ushort_t*)(W + o); o += 327680;
    ushort_t* uh    = (ushort_t*)(W + o); o += 327680;
    ushort_t* ul    = (ushort_t*)(W + o); o += 327680;
    ushort_t* omh_r = (ushort_t*)(W + o); o += 2097152;
    ushort_t* oml_r = (ushort_t*)(W + o); o += 2097152;
    ushort_t* omTh  = (ushort_t*)(W + o); o += 2097152;
    ushort_t* omTl  = (ushort_t*)(W + o); o += 2097152;
    ushort_t* omh_sw= (ushort_t*)(W + o); o += 2097152;   // ~12.49 MB so far
    ushort_t* xh    = (ushort_t*)(W + o);                 // +16 MB -> ~29.3 MB

    const int tier = (ws_size >= (size_t)30 * 1024 * 1024) ? 2
                   : (ws_size >= (size_t)13 * 1024 * 1024) ? 1 : 0;

    if (tier >= 1) {
        // zero-init of sqx/sqp is fused into k_prep1 (block 266) — the
        // runtime's 33KB fillBuffer kernel cost ~41us per graph replay.
        k_prep1<<<267, 256, 0, stream>>>(om, prot, omh_r, oml_r, omTh, omTl,
                                         omh_sw, phl, pll, (float4*)W);
        k_zp2  <<<160, 256, 0, stream>>>(phl, pll, omh_r, oml_r, zph, zpl, sqp);
        k_u2   <<<160, 256, 0, stream>>>(zph, zpl, omTh, omTl, uh, ul);
        if (tier == 2) {
            k_cvt_sw<<<4096, 256, 0, stream>>>(x, xh);
            k_z_sqx2<<<dim3(64, 8), 256, 0, stream>>>(xh, omh_sw, sqx);
            k_dist3<<<512, 256, 0, stream>>>(xh, uh, sqx, sqp, dist, pred);
        } else {
            k_z_sqx <<<dim3(64, 8), 256, 0, stream>>>(x, om, sqx);
            k_dist2<<<512, 256, 0, stream>>>(x, uh, sqx, sqp, dist, pred);
        }
    } else {
        // tier-0: R3 path (ws >= ~1.35 MB known-good)
        float* wsf = (float*)d_ws;
        float* zp  = wsf + 8448;
        float* u   = wsf + 172288;
        ushort_t* uh0 = (ushort_t*)(wsf + 8448);
        ushort_t* ul0 = uh0 + 163840;
        hipMemsetAsync(wsf, 0, 33792, stream);
        hipMemsetAsync(u, 0, (size_t)P_ * F_ * sizeof(float), stream);
        k_proj  <<<64, 256, 0, stream>>>(prot, om, zp, sqp);
        k_u     <<<dim3(8, 5, 8), 128, 0, stream>>>(zp, om, u);
        k_usplit<<<160, 256, 0, stream>>>(u, uh0, ul0);
        k_z_sqx <<<dim3(64, 8), 256, 0, stream>>>(x, om, sqx);
        k_dist2 <<<512, 256, 0, stream>>>(x, uh0, sqx, sqp, dist, pred);
    }
}